// Round 7
// baseline (903.451 us; speedup 1.0000x reference)
//
#include <hip/hip_runtime.h>
#include <hip/hip_bf16.h>
#include <math.h>

typedef __attribute__((ext_vector_type(8))) short short8;
typedef __attribute__((ext_vector_type(4))) float f32x4;

#define MFMA16(a, b, c) __builtin_amdgcn_mfma_f32_16x16x32_bf16((a), (b), (c), 0, 0, 0)

#define BB 256
#define TT 64
#define VOCAB 10000
#define WORD 512
#define RNN 512
#define NC 2560          /* 2048 gates + 512 sentinel-gate pre */
#define NV 10001
#define NVP 10016
#define NTILES 626       /* NVP/16 */

typedef unsigned long long ull;
union U16 { ull u[2]; short8 s8; };

// fast transcendentals: v_exp + v_rcp (absmax budget 0.0625 >> their ~1e-6 error)
__device__ __forceinline__ float sigf(float x) {
    return __builtin_amdgcn_rcpf(1.f + __expf(-x));
}
__device__ __forceinline__ float tanhf_fast(float x) {
    // 1 - 2/(e^{2x}+1); saturates correctly at +-1 (inf/0 through rcp)
    return 1.f - 2.f * __builtin_amdgcn_rcpf(__expf(2.f * x) + 1.f);
}
__device__ __forceinline__ float bf2f(short s) {
    union { unsigned int u; float f; } v;
    v.u = ((unsigned int)(unsigned short)s) << 16;
    return v.f;
}
__device__ __forceinline__ short f2bfs(float x) {
    __hip_bfloat16 h = __float2bfloat16(x);
    return *reinterpret_cast<short*>(&h);
}

// async global->LDS, 16B per lane. lds dest = wave-uniform base + lane*16 (HW rule).
__device__ __forceinline__ void gload_lds16(const void* g, void* l) {
    __builtin_amdgcn_global_load_lds((const __attribute__((address_space(1))) void*)g,
                                     (__attribute__((address_space(3))) void*)l, 16, 0, 0);
}

// stage one 16KB fragment-order tile: 4 waves x 4KB each
__device__ __forceinline__ void stage_tile(const short8* gsrc, void* lbuf, int w, int lane) {
    const char* g = (const char*)gsrc + w * 4096 + lane * 16;
    char* l = (char*)lbuf + w * 4096;
#pragma unroll
    for (int i = 0; i < 4; i++) gload_lds16(g + i * 1024, l + i * 1024);
}

// ---------------- prep kernels ----------------

// dst[n][k] = (float->bf16) src[k][n]; zero-fill for n in [N, dstN)
__global__ void transpose_cvt(const float* __restrict__ src, int K, int N, int ld,
                              __hip_bfloat16* __restrict__ dst, int dst_ld, int dstN) {
    __shared__ float tile[32][33];
    int k0 = blockIdx.y * 32, n0 = blockIdx.x * 32;
    int tx = threadIdx.x, ty = threadIdx.y;   // 32 x 8
#pragma unroll
    for (int i = 0; i < 32; i += 8) {
        int k = k0 + ty + i, n = n0 + tx;
        tile[ty + i][tx] = (k < K && n < N) ? src[(size_t)k * ld + n] : 0.f;
    }
    __syncthreads();
#pragma unroll
    for (int i = 0; i < 32; i += 8) {
        int n = n0 + ty + i, k = k0 + tx;
        if (n < dstN && k < K) dst[(size_t)n * dst_ld + k] = __float2bfloat16(tile[tx][ty + i]);
    }
}

// [ntiles*16][512] ([N][K]) -> fragment order: dst[ct][kt][lane] = src[(ct*16+(l&15))][kt*32+(l>>4)*8 ..+7]
__global__ void swizzle_frag(const short8* __restrict__ src, short8* __restrict__ dst, int ntiles) {
    int t = blockIdx.x * 256 + threadIdx.x;
    if (t >= ntiles * 1024) return;
    int ct = t >> 10, r = t & 1023, kt = r >> 6, l = r & 63;
    int li = l & 15, q = l >> 4;
    dst[t] = src[(size_t)(ct * 16 + li) * 64 + kt * 4 + q];
}

__global__ void cvt_vis(const float* __restrict__ v, __hip_bfloat16* __restrict__ d) {
    int idx = blockIdx.x * 256 + threadIdx.x;   // 262144
    d[idx] = __float2bfloat16(v[idx]);
}

// visC[256][2560] = vis_bf16 @ visW + bias (b_lstm for n<2048 else vis2g_b)
__global__ __launch_bounds__(256) void gemm_vis(const __hip_bfloat16* __restrict__ A,
                                                const __hip_bfloat16* __restrict__ Bt,
                                                const float* __restrict__ b_lstm,
                                                const float* __restrict__ vis2g_b,
                                                float* __restrict__ C) {
    int wid = blockIdx.x * 4 + (threadIdx.x >> 6);   // 2560 waves: 16 x 160 tiles
    int mt = wid / 160, nt = wid % 160;
    int lane = threadIdx.x & 63, li = lane & 15, q = lane >> 4;
    const short8* Ap = (const short8*)A + (mt * 16 + li) * 128 + q;   // ld 1024 -> 128 chunks
    const short8* Bp = (const short8*)Bt + (nt * 16 + li) * 128 + q;
    f32x4 acc = {0.f, 0.f, 0.f, 0.f};
#pragma unroll
    for (int kk = 0; kk < 128; kk += 4) acc = MFMA16(Ap[kk], Bp[kk], acc);
    int col = nt * 16 + li;
    float bias = (col < 2048) ? b_lstm[col] : vis2g_b[col - 2048];
#pragma unroll
    for (int r = 0; r < 4; r++) {
        int row = mt * 16 + q * 4 + r;
        C[row * NC + col] = acc[r] + bias;
    }
}

// preF in TRANSPOSED-fragment order: preF[((rowtile*160 + ct)*256 + lane*4) + r]
//   = pre[row = rowtile*16 + (lane&15)][col = ct*16 + (lane>>4)*4 + r]
__global__ __launch_bounds__(256) void pre_gemm(const int* __restrict__ seqz,
                                                const float* __restrict__ emb,
                                                const short8* __restrict__ Bsw,   // 160 tiles, frag order
                                                const float* __restrict__ visC,
                                                __hip_bfloat16* __restrict__ preF) {
    __shared__ short8 lds[2][1024];
    int w = threadIdx.x >> 6, lane = threadIdx.x & 63, li = lane & 15, q = lane >> 4;
    int r0 = blockIdx.x * 128 + w * 32;

    short8 a0[16], a1[16];
    {
        int row = r0 + li;
        int t = row >> 8, b = row & 255;
        int wid_ = (t == 0) ? (VOCAB + 1) : seqz[b * TT + (t - 1)];
        const float* er = emb + (size_t)wid_ * WORD + q * 8;
#pragma unroll
        for (int kt = 0; kt < 16; kt++) {
            float4 f0 = ((const float4*)(er + kt * 32))[0];
            float4 f1 = ((const float4*)(er + kt * 32))[1];
            short8 v; v[0]=f2bfs(f0.x); v[1]=f2bfs(f0.y); v[2]=f2bfs(f0.z); v[3]=f2bfs(f0.w);
            v[4]=f2bfs(f1.x); v[5]=f2bfs(f1.y); v[6]=f2bfs(f1.z); v[7]=f2bfs(f1.w);
            a0[kt] = v;
        }
        row = r0 + 16 + li; t = row >> 8; b = row & 255;
        wid_ = (t == 0) ? (VOCAB + 1) : seqz[b * TT + (t - 1)];
        er = emb + (size_t)wid_ * WORD + q * 8;
#pragma unroll
        for (int kt = 0; kt < 16; kt++) {
            float4 f0 = ((const float4*)(er + kt * 32))[0];
            float4 f1 = ((const float4*)(er + kt * 32))[1];
            short8 v; v[0]=f2bfs(f0.x); v[1]=f2bfs(f0.y); v[2]=f2bfs(f0.z); v[3]=f2bfs(f0.w);
            v[4]=f2bfs(f1.x); v[5]=f2bfs(f1.y); v[6]=f2bfs(f1.z); v[7]=f2bfs(f1.w);
            a1[kt] = v;
        }
    }

    int t0 = blockIdx.y * 20, t1 = t0 + 20;   // 8 chunks x 20 = 160
    stage_tile(Bsw + (size_t)t0 * 1024, lds[0], w, lane);
    int ib = 0;
    for (int ct = t0; ct < t1; ++ct, ib ^= 1) {
        __syncthreads();
        if (ct + 1 < t1) stage_tile(Bsw + (size_t)(ct + 1) * 1024, lds[ib ^ 1], w, lane);
        const short8* B = lds[ib];
        f32x4 c0 = {0.f,0.f,0.f,0.f}, c1 = {0.f,0.f,0.f,0.f};
#pragma unroll
        for (int kt = 0; kt < 16; kt++) {
            short8 bv = B[kt * 64 + lane];
            // TRANSPOSED: A = W-frag, B = emb-frag -> lane holds batch row li, gate cols ct*16+q*4..+3
            c0 = MFMA16(bv, a0[kt], c0);
            c1 = MFMA16(bv, a1[kt], c1);
        }
        int col0 = ct * 16 + q * 4;
        size_t tb0 = ((size_t)(r0 >> 4) * 160 + ct) * 256 + lane * 4;
        size_t tb1 = tb0 + (size_t)160 * 256;
        float4 v0 = *(const float4*)(visC + ((r0 + li) & 255) * NC + col0);
        float4 v1 = *(const float4*)(visC + ((r0 + 16 + li) & 255) * NC + col0);
        preF[tb0 + 0] = __float2bfloat16(c0[0] + v0.x);
        preF[tb0 + 1] = __float2bfloat16(c0[1] + v0.y);
        preF[tb0 + 2] = __float2bfloat16(c0[2] + v0.z);
        preF[tb0 + 3] = __float2bfloat16(c0[3] + v0.w);
        preF[tb1 + 0] = __float2bfloat16(c1[0] + v1.x);
        preF[tb1 + 1] = __float2bfloat16(c1[1] + v1.y);
        preF[tb1 + 2] = __float2bfloat16(c1[2] + v1.z);
        preF[tb1 + 3] = __float2bfloat16(c1[3] + v1.w);
    }
}

// ---------------- persistent recurrence kernel (per-step buffers, data-poll) ----------------
// 512 blocks x 1 wave (cooperative). Wave (bt,jt): batch rows bt*16..+15, gate cols
// jt*16..+15 of the 5 gate blocks. bt = wid>>5 (contiguous; round-4 known-good mapping).
//
// Sync v5: NO flags, NO drains, NO in-loop poison. hbuf has ONE 256KB buffer PER STEP
// (65 total, 17MB), pre-poisoned 0xFF by host memset (bf16 0xFFFF = -NaN, never produced
// by __float2bfloat16); buffer 0 pre-zeroed (step-0 h input).
//   producer: h store (sc0sc1 relaxed -> L3) + S store. Nothing else. The store's own
//             completion is the publish.
//   consumer: poll-gather its 32x8B fragments of buffer t until no chunk is poison
//             (8B system stores/loads are tear-free). The successful poll IS the gather
//             -> sync+data in one L3 round trip; retry = 1 RTT.
//   no WAR hazards: each step writes a fresh buffer. Self-read-after-write resolved by
//   the retry loop. Poll bounded (8000): logic bug -> fast wrong answer, never a hang.
__global__ __launch_bounds__(64, 1) void lstm_persist(const short8* __restrict__ WHsw,
                                                      const __hip_bfloat16* __restrict__ preF,
                                                      char* __restrict__ hbuf,
                                                      __hip_bfloat16* __restrict__ S) {
    __shared__ short8 ldsB[4096];   // 64 KB: 4 gate W-tiles x 16KB, fragment order
    int wid = blockIdx.x;           // 0..511
    int bt = wid >> 5, jt = wid & 31;
    int lane = threadIdx.x;
    int li = lane & 15, q = lane >> 4;

    // stage W tiles for gates 0..3 -> LDS (linear copy of frag-order tiles)
#pragma unroll
    for (int g = 0; g < 4; ++g) {
        const char* src = (const char*)(WHsw + (size_t)(g * 32 + jt) * 1024) + lane * 16;
        char* dst = (char*)ldsB + g * 16384;
#pragma unroll
        for (int i = 0; i < 16; ++i) gload_lds16(src + i * 1024, dst + i * 1024);
    }
    // sentinel-gate W tile -> registers
    short8 b4[16];
    const short8* B4 = WHsw + (size_t)(128 + jt) * 1024 + lane;
#pragma unroll
    for (int kt = 0; kt < 16; ++kt) b4[kt] = B4[kt * 64];
    __syncthreads();   // drains vmcnt -> gload_lds data usable

    f32x4 cacc = {0.f, 0.f, 0.f, 0.f};    // c[row bt*16+li][cols jt*16+q*4..+3]

    int hin  = (bt * 16 + li) * 1024 + q * 16;                // h frag load base (bytes)
    int hout = (bt * 16 + li) * 1024 + (jt * 16 + q * 4) * 2; // h/S store base (bytes)

    // preF stream: ull index = t*163840 + bt*10240 + g*2048 + jt*64 + lane
    const ull* ppw = (const ull*)preF + ((size_t)bt * 160 + jt) * 64 + lane;

    ull ppA[5], ppB[5];
#pragma unroll
    for (int g = 0; g < 5; ++g) ppA[g] = ppw[g * 2048];

    ull hf[32];

#define LSTM_STEP(T, PPC, PPN)                                                     \
  {                                                                                \
    const ull* hp = (const ull*)(hbuf + (size_t)(T) * 262144 + hin);               \
    int it = 0;                                                                    \
    while (true) {                                                                 \
      int ok = 1;                                                                  \
      _Pragma("unroll") for (int kt = 0; kt < 16; ++kt) {                          \
        hf[2 * kt]     = __hip_atomic_load(hp + kt * 8, __ATOMIC_RELAXED,          \
                                           __HIP_MEMORY_SCOPE_SYSTEM);             \
        hf[2 * kt + 1] = __hip_atomic_load(hp + kt * 8 + 1, __ATOMIC_RELAXED,      \
                                           __HIP_MEMORY_SCOPE_SYSTEM);             \
        ok &= (hf[2 * kt] != ~0ull) & (hf[2 * kt + 1] != ~0ull);                   \
      }                                                                            \
      if (__all(ok)) break;                                                        \
      if (++it > 8000) break;   /* bounded: fail loud, never hang */               \
      __builtin_amdgcn_s_sleep(1);                                                 \
    }                                                                              \
    if ((T) + 1 < TT) {                                                            \
      const ull* pn = ppw + (size_t)((T) + 1) * 163840;                            \
      _Pragma("unroll") for (int g = 0; g < 5; ++g) (PPN)[g] = pn[g * 2048];       \
    }                                                                              \
    f32x4 g0 = {0.f, 0.f, 0.f, 0.f}, g1 = g0, g2 = g0, g3 = g0, g4 = g0;           \
    _Pragma("unroll") for (int kt = 0; kt < 16; ++kt) {                            \
      U16 hv; hv.u[0] = hf[2 * kt]; hv.u[1] = hf[2 * kt + 1];                      \
      short8 bv = hv.s8;                                                           \
      g0 = MFMA16(ldsB[       kt * 64 + lane], bv, g0);                            \
      g1 = MFMA16(ldsB[1024 + kt * 64 + lane], bv, g1);                            \
      g2 = MFMA16(ldsB[2048 + kt * 64 + lane], bv, g2);                            \
      g3 = MFMA16(ldsB[3072 + kt * 64 + lane], bv, g3);                            \
      g4 = MFMA16(b4[kt], bv, g4);                                                 \
    }                                                                              \
    ull hvout = 0ull, svout = 0ull;                                                \
    _Pragma("unroll") for (int r = 0; r < 4; ++r) {                                \
      float ig = sigf(g0[r] + bf2f((short)((PPC)[0] >> (16 * r))));                \
      float fg = sigf(g1[r] + bf2f((short)((PPC)[1] >> (16 * r))));                \
      float gg = tanhf_fast(g2[r] + bf2f((short)((PPC)[2] >> (16 * r))));          \
      float og = sigf(g3[r] + bf2f((short)((PPC)[3] >> (16 * r))));                \
      float gp = sigf(g4[r] + bf2f((short)((PPC)[4] >> (16 * r))));                \
      float cn = fg * cacc[r] + ig * gg;                                           \
      float tc = tanhf_fast(cn);                                                   \
      cacc[r] = cn;                                                                \
      hvout |= ((ull)(unsigned short)f2bfs(og * tc)) << (16 * r);                  \
      svout |= ((ull)(unsigned short)f2bfs(gp * tc)) << (16 * r);                  \
    }                                                                              \
    __hip_atomic_store((ull*)(hbuf + (size_t)((T) + 1) * 262144 + hout), hvout,    \
                       __ATOMIC_RELAXED, __HIP_MEMORY_SCOPE_SYSTEM);               \
    *(ull*)((char*)S + (size_t)(T) * 262144 + hout) = svout;                       \
  }

    for (int t = 0; t < TT; t += 2) {
        LSTM_STEP(t,     ppA, ppB);
        LSTM_STEP(t + 1, ppB, ppA);
    }
#undef LSTM_STEP
}

// ---------------- fused output GEMM + sum-exp ----------------

__global__ __launch_bounds__(256) void lse_gemm(const short8* __restrict__ S8,
                                                const short8* __restrict__ Bsw,
                                                const float* __restrict__ ob,
                                                float* __restrict__ sumexp) {
    __shared__ short8 lds[2][1024];
    int w = threadIdx.x >> 6, lane = threadIdx.x & 63, li = lane & 15, q = lane >> 4;
    int r0 = blockIdx.x * 128 + w * 32;
    short8 a0[16], a1[16];
    const short8* Sp0 = S8 + (size_t)(r0 + li) * 64 + q;
    const short8* Sp1 = S8 + (size_t)(r0 + 16 + li) * 64 + q;
#pragma unroll
    for (int kt = 0; kt < 16; kt++) { a0[kt] = Sp0[kt * 4]; a1[kt] = Sp1[kt * 4]; }

    float s0[4] = {0.f,0.f,0.f,0.f}, s1[4] = {0.f,0.f,0.f,0.f};
    int t0 = blockIdx.y * 40;
    int t1 = t0 + 40 < NTILES ? t0 + 40 : NTILES;   // last chunk = 26

    stage_tile(Bsw + (size_t)t0 * 1024, lds[0], w, lane);
    int ib = 0;
    for (int ct = t0; ct < t1; ++ct, ib ^= 1) {
        __syncthreads();
        if (ct + 1 < t1) stage_tile(Bsw + (size_t)(ct + 1) * 1024, lds[ib ^ 1], w, lane);
        const short8* B = lds[ib];
        f32x4 c0 = {0.f,0.f,0.f,0.f}, c1 = {0.f,0.f,0.f,0.f};
#pragma unroll
        for (int kt = 0; kt < 16; kt++) {
            short8 bv = B[kt * 64 + lane];
            c0 = MFMA16(a0[kt], bv, c0);
            c1 = MFMA16(a1[kt], bv, c1);
        }
        int col = ct * 16 + li;
        if (col < NV) {
            float obv = ob[col];
#pragma unroll
            for (int r = 0; r < 4; r++) {
                s0[r] += __expf(c0[r] + obv);
                s1[r] += __expf(c1[r] + obv);
            }
        }
    }
#pragma unroll
    for (int off = 1; off < 16; off <<= 1) {
#pragma unroll
        for (int r = 0; r < 4; r++) { s0[r] += __shfl_xor(s0[r], off); s1[r] += __shfl_xor(s1[r], off); }
    }
    if (li == 0) {
#pragma unroll
        for (int r = 0; r < 4; r++) {
            atomicAdd(&sumexp[r0 + q * 4 + r], s0[r]);
            atomicAdd(&sumexp[r0 + 16 + q * 4 + r], s1[r]);
        }
    }
}

// out[row] = mask * (dot(S[row], out_W[:,tgt]) + ob[tgt] - log(sumexp[row]))
__global__ __launch_bounds__(256) void finalize_k(const __hip_bfloat16* __restrict__ S,
                                                  const __hip_bfloat16* __restrict__ Wt,
                                                  const float* __restrict__ ob,
                                                  const int* __restrict__ seqz,
                                                  const float* __restrict__ sumexp,
                                                  float* __restrict__ out) {
    int w = threadIdx.x >> 6, lane = threadIdx.x & 63;
    int row = blockIdx.x * 4 + w;        // 16384 rows, row = t*256 + b
    int t = row >> 8, b = row & 255;
    int tgt = seqz[b * TT + t];
    short8 sv = ((const short8*)(S + (size_t)row * 512))[lane];
    short8 wv = ((const short8*)(Wt + (size_t)tgt * 512))[lane];
    float d = 0.f;
#pragma unroll
    for (int i = 0; i < 8; i++) d += bf2f(sv[i]) * bf2f(wv[i]);
#pragma unroll
    for (int off = 1; off < 64; off <<= 1) d += __shfl_xor(d, off);
    if (lane == 0) {
        bool mk = (t == 0) || (seqz[b * TT + t - 1] != 0);
        out[row] = mk ? (d + ob[tgt] - logf(sumexp[row])) : 0.f;
    }
}

// ---------------- host ----------------

extern "C" void kernel_launch(void* const* d_in, const int* in_sizes, int n_in,
                              void* d_out, int out_size, void* d_ws, size_t ws_size,
                              hipStream_t stream) {
    const float* vis     = (const float*)d_in[0];
    const int*   seqz    = (const int*)d_in[1];
    const float* emb     = (const float*)d_in[2];
    const float* W_ih    = (const float*)d_in[3];
    const float* W_hh    = (const float*)d_in[4];
    const float* b_lstm  = (const float*)d_in[5];
    const float* vis2g_W = (const float*)d_in[6];
    const float* vis2g_b = (const float*)d_in[7];
    const float* w2g_W   = (const float*)d_in[8];
    const float* h2g_W   = (const float*)d_in[9];
    const float* out_W   = (const float*)d_in[10];
    const float* out_b   = (const float*)d_in[11];
    float* out = (float*)d_out;

    char* p = (char*)d_ws;
    auto carve = [&](size_t bytes) {
        void* r = (void*)p;
        p += (bytes + 255) & ~(size_t)255;
        return r;
    };
    __hip_bfloat16* WcatW = (__hip_bfloat16*)carve((size_t)NC * 512 * 2);       // [2560][512]
    __hip_bfloat16* WcatH = (__hip_bfloat16*)carve((size_t)NC * 512 * 2);       // [2560][512]
    __hip_bfloat16* visWt = (__hip_bfloat16*)carve((size_t)NC * 1024 * 2);      // [2560][1024]
    __hip_bfloat16* outWt = (__hip_bfloat16*)carve((size_t)NVP * 512 * 2);      // [10016][512]
    short8*         outSw = (short8*)carve((size_t)NTILES * 16384);             // frag order
    short8*         preBsw= (short8*)carve((size_t)160 * 16384);                // frag order
    short8*         WHsw  = (short8*)carve((size_t)160 * 16384);                // frag order
    __hip_bfloat16* visB  = (__hip_bfloat16*)carve((size_t)256 * 1024 * 2);
    float*          visC  = (float*)carve((size_t)256 * NC * 4);
    __hip_bfloat16* preF  = (__hip_bfloat16*)carve((size_t)TT * 256 * NC * 2);  // 84 MB, frag order
    char*           hbuf  = (char*)carve((size_t)(TT + 1) * 262144);            // 65 per-step h buffers, 17 MB
    __hip_bfloat16* S     = (__hip_bfloat16*)carve((size_t)TT * 256 * 512 * 2);
    float*          sume  = (float*)carve((size_t)TT * 256 * 4);

    dim3 tb(32, 8);
    // WcatW: word -> [gates | w2g];  WcatH: h -> [gates | h2g]   (both [2560][512] = [N][K])
    transpose_cvt<<<dim3(64, 16), tb, 0, stream>>>(W_ih + 1024 * 2048, 512, 2048, 2048, WcatW, 512, 2048);
    transpose_cvt<<<dim3(16, 16), tb, 0, stream>>>(w2g_W, 512, 512, 512, WcatW + 2048 * 512, 512, 512);
    transpose_cvt<<<dim3(64, 16), tb, 0, stream>>>(W_hh, 512, 2048, 2048, WcatH, 512, 2048);
    transpose_cvt<<<dim3(16, 16), tb, 0, stream>>>(h2g_W, 512, 512, 512, WcatH + 2048 * 512, 512, 512);
    // visWt: vis -> [gates | vis2g]  [2560][1024]
    transpose_cvt<<<dim3(64, 32), tb, 0, stream>>>(W_ih, 1024, 2048, 2048, visWt, 1024, 2048);
    transpose_cvt<<<dim3(16, 32), tb, 0, stream>>>(vis2g_W, 1024, 512, 512, visWt + 2048 * 1024, 1024, 512);
    // out_W transposed, zero-padded to 10016 rows
    transpose_cvt<<<dim3(313, 16), tb, 0, stream>>>(out_W, 512, NV, NV, outWt, 512, NVP);
    // fragment-order swizzles
    swizzle_frag<<<2504, 256, 0, stream>>>((const short8*)outWt, outSw, NTILES);
    swizzle_frag<<<640, 256, 0, stream>>>((const short8*)WcatW, preBsw, 160);
    swizzle_frag<<<640, 256, 0, stream>>>((const short8*)WcatH, WHsw, 160);

    // h step-buffers: buffer 0 = zeros (step-0 input), buffers 1..64 = 0xFF poison
    hipMemsetAsync(hbuf, 0, 262144, stream);
    hipMemsetAsync(hbuf + 262144, 0xFF, (size_t)TT * 262144, stream);
    hipMemsetAsync(sume, 0, (size_t)TT * 256 * 4, stream);

    cvt_vis<<<1024, 256, 0, stream>>>(vis, visB);
    gemm_vis<<<640, 256, 0, stream>>>(visB, visWt, b_lstm, vis2g_b, visC);
    pre_gemm<<<dim3(128, 8), 256, 0, stream>>>(seqz, emb, preBsw, visC, preF);

    // all 64 recurrence steps in one cooperative persistent kernel
    {
        const short8* WHsw_c = (const short8*)WHsw;
        const __hip_bfloat16* preF_c = (const __hip_bfloat16*)preF;
        char* hbufa = hbuf;
        __hip_bfloat16* Sa = S;
        void* kargs[4] = { &WHsw_c, &preF_c, &hbufa, &Sa };
        hipLaunchCooperativeKernel((void*)lstm_persist, dim3(512), dim3(64), kargs, 0, stream);
    }

    lse_gemm<<<dim3(128, 16), 256, 0, stream>>>((const short8*)S, outSw, out_b, sume);
    finalize_k<<<4096, 256, 0, stream>>>(S, outWt, out_b, seqz, sume, out);
}

// Round 9
// 807.530 us; speedup vs baseline: 1.1188x; 1.1188x over previous
//
#include <hip/hip_runtime.h>
#include <hip/hip_bf16.h>
#include <math.h>

typedef __attribute__((ext_vector_type(8))) short short8;
typedef __attribute__((ext_vector_type(4))) float f32x4;

#define MFMA16(a, b, c) __builtin_amdgcn_mfma_f32_16x16x32_bf16((a), (b), (c), 0, 0, 0)

#define BB 256
#define TT 64
#define VOCAB 10000
#define WORD 512
#define RNN 512
#define NC 2560          /* 2048 gates + 512 sentinel-gate pre */
#define NV 10001
#define NVP 10016
#define NTILES 626       /* NVP/16 */

typedef unsigned long long ull;
union U16 { ull u[2]; short8 s8; };

// fast transcendentals (r7-verified: absmax 0.0625, same as libm path)
__device__ __forceinline__ float sigf(float x) {
    return __builtin_amdgcn_rcpf(1.f + __expf(-x));
}
__device__ __forceinline__ float tanhf_fast(float x) {
    // 1 - 2/(e^{2x}+1); saturates correctly at +-1
    return 1.f - 2.f * __builtin_amdgcn_rcpf(__expf(2.f * x) + 1.f);
}
__device__ __forceinline__ float bf2f(short s) {
    union { unsigned int u; float f; } v;
    v.u = ((unsigned int)(unsigned short)s) << 16;
    return v.f;
}
__device__ __forceinline__ short f2bfs(float x) {
    __hip_bfloat16 h = __float2bfloat16(x);
    return *reinterpret_cast<short*>(&h);
}

// async global->LDS, 16B per lane. lds dest = wave-uniform base + lane*16 (HW rule).
__device__ __forceinline__ void gload_lds16(const void* g, void* l) {
    __builtin_amdgcn_global_load_lds((const __attribute__((address_space(1))) void*)g,
                                     (__attribute__((address_space(3))) void*)l, 16, 0, 0);
}

// stage one 16KB fragment-order tile: 4 waves x 4KB each
__device__ __forceinline__ void stage_tile(const short8* gsrc, void* lbuf, int w, int lane) {
    const char* g = (const char*)gsrc + w * 4096 + lane * 16;
    char* l = (char*)lbuf + w * 4096;
#pragma unroll
    for (int i = 0; i < 4; i++) gload_lds16(g + i * 1024, l + i * 1024);
}

// ---------------- prep kernels ----------------

// dst[n][k] = (float->bf16) src[k][n]; zero-fill for n in [N, dstN)
__global__ void transpose_cvt(const float* __restrict__ src, int K, int N, int ld,
                              __hip_bfloat16* __restrict__ dst, int dst_ld, int dstN) {
    __shared__ float tile[32][33];
    int k0 = blockIdx.y * 32, n0 = blockIdx.x * 32;
    int tx = threadIdx.x, ty = threadIdx.y;   // 32 x 8
#pragma unroll
    for (int i = 0; i < 32; i += 8) {
        int k = k0 + ty + i, n = n0 + tx;
        tile[ty + i][tx] = (k < K && n < N) ? src[(size_t)k * ld + n] : 0.f;
    }
    __syncthreads();
#pragma unroll
    for (int i = 0; i < 32; i += 8) {
        int n = n0 + ty + i, k = k0 + tx;
        if (n < dstN && k < K) dst[(size_t)n * dst_ld + k] = __float2bfloat16(tile[tx][ty + i]);
    }
}

// [ntiles*16][512] ([N][K]) -> fragment order: dst[ct][kt][lane] = src[(ct*16+(l&15))][kt*32+(l>>4)*8 ..+7]
__global__ void swizzle_frag(const short8* __restrict__ src, short8* __restrict__ dst, int ntiles) {
    int t = blockIdx.x * 256 + threadIdx.x;
    if (t >= ntiles * 1024) return;
    int ct = t >> 10, r = t & 1023, kt = r >> 6, l = r & 63;
    int li = l & 15, q = l >> 4;
    dst[t] = src[(size_t)(ct * 16 + li) * 64 + kt * 4 + q];
}

__global__ void cvt_vis(const float* __restrict__ v, __hip_bfloat16* __restrict__ d) {
    int idx = blockIdx.x * 256 + threadIdx.x;   // 262144
    d[idx] = __float2bfloat16(v[idx]);
}

// visC[256][2560] = vis_bf16 @ visW + bias (b_lstm for n<2048 else vis2g_b)
__global__ __launch_bounds__(256) void gemm_vis(const __hip_bfloat16* __restrict__ A,
                                                const __hip_bfloat16* __restrict__ Bt,
                                                const float* __restrict__ b_lstm,
                                                const float* __restrict__ vis2g_b,
                                                float* __restrict__ C) {
    int wid = blockIdx.x * 4 + (threadIdx.x >> 6);   // 2560 waves: 16 x 160 tiles
    int mt = wid / 160, nt = wid % 160;
    int lane = threadIdx.x & 63, li = lane & 15, q = lane >> 4;
    const short8* Ap = (const short8*)A + (mt * 16 + li) * 128 + q;   // ld 1024 -> 128 chunks
    const short8* Bp = (const short8*)Bt + (nt * 16 + li) * 128 + q;
    f32x4 acc = {0.f, 0.f, 0.f, 0.f};
#pragma unroll
    for (int kk = 0; kk < 128; kk += 4) acc = MFMA16(Ap[kk], Bp[kk], acc);
    int col = nt * 16 + li;
    float bias = (col < 2048) ? b_lstm[col] : vis2g_b[col - 2048];
#pragma unroll
    for (int r = 0; r < 4; r++) {
        int row = mt * 16 + q * 4 + r;
        C[row * NC + col] = acc[r] + bias;
    }
}

// preF in TRANSPOSED-fragment order: preF[((rowtile*160 + ct)*256 + lane*4) + r]
//   = pre[row = rowtile*16 + (lane&15)][col = ct*16 + (lane>>4)*4 + r]
__global__ __launch_bounds__(256) void pre_gemm(const int* __restrict__ seqz,
                                                const float* __restrict__ emb,
                                                const short8* __restrict__ Bsw,   // 160 tiles, frag order
                                                const float* __restrict__ visC,
                                                __hip_bfloat16* __restrict__ preF) {
    __shared__ short8 lds[2][1024];
    int w = threadIdx.x >> 6, lane = threadIdx.x & 63, li = lane & 15, q = lane >> 4;
    int r0 = blockIdx.x * 128 + w * 32;

    short8 a0[16], a1[16];
    {
        int row = r0 + li;
        int t = row >> 8, b = row & 255;
        int wid_ = (t == 0) ? (VOCAB + 1) : seqz[b * TT + (t - 1)];
        const float* er = emb + (size_t)wid_ * WORD + q * 8;
#pragma unroll
        for (int kt = 0; kt < 16; kt++) {
            float4 f0 = ((const float4*)(er + kt * 32))[0];
            float4 f1 = ((const float4*)(er + kt * 32))[1];
            short8 v; v[0]=f2bfs(f0.x); v[1]=f2bfs(f0.y); v[2]=f2bfs(f0.z); v[3]=f2bfs(f0.w);
            v[4]=f2bfs(f1.x); v[5]=f2bfs(f1.y); v[6]=f2bfs(f1.z); v[7]=f2bfs(f1.w);
            a0[kt] = v;
        }
        row = r0 + 16 + li; t = row >> 8; b = row & 255;
        wid_ = (t == 0) ? (VOCAB + 1) : seqz[b * TT + (t - 1)];
        er = emb + (size_t)wid_ * WORD + q * 8;
#pragma unroll
        for (int kt = 0; kt < 16; kt++) {
            float4 f0 = ((const float4*)(er + kt * 32))[0];
            float4 f1 = ((const float4*)(er + kt * 32))[1];
            short8 v; v[0]=f2bfs(f0.x); v[1]=f2bfs(f0.y); v[2]=f2bfs(f0.z); v[3]=f2bfs(f0.w);
            v[4]=f2bfs(f1.x); v[5]=f2bfs(f1.y); v[6]=f2bfs(f1.z); v[7]=f2bfs(f1.w);
            a1[kt] = v;
        }
    }

    int t0 = blockIdx.y * 20, t1 = t0 + 20;   // 8 chunks x 20 = 160
    stage_tile(Bsw + (size_t)t0 * 1024, lds[0], w, lane);
    int ib = 0;
    for (int ct = t0; ct < t1; ++ct, ib ^= 1) {
        __syncthreads();
        if (ct + 1 < t1) stage_tile(Bsw + (size_t)(ct + 1) * 1024, lds[ib ^ 1], w, lane);
        const short8* B = lds[ib];
        f32x4 c0 = {0.f,0.f,0.f,0.f}, c1 = {0.f,0.f,0.f,0.f};
#pragma unroll
        for (int kt = 0; kt < 16; kt++) {
            short8 bv = B[kt * 64 + lane];
            // TRANSPOSED: A = W-frag, B = emb-frag -> lane holds batch row li, gate cols ct*16+q*4..+3
            c0 = MFMA16(bv, a0[kt], c0);
            c1 = MFMA16(bv, a1[kt], c1);
        }
        int col0 = ct * 16 + q * 4;
        size_t tb0 = ((size_t)(r0 >> 4) * 160 + ct) * 256 + lane * 4;
        size_t tb1 = tb0 + (size_t)160 * 256;
        float4 v0 = *(const float4*)(visC + ((r0 + li) & 255) * NC + col0);
        float4 v1 = *(const float4*)(visC + ((r0 + 16 + li) & 255) * NC + col0);
        preF[tb0 + 0] = __float2bfloat16(c0[0] + v0.x);
        preF[tb0 + 1] = __float2bfloat16(c0[1] + v0.y);
        preF[tb0 + 2] = __float2bfloat16(c0[2] + v0.z);
        preF[tb0 + 3] = __float2bfloat16(c0[3] + v0.w);
        preF[tb1 + 0] = __float2bfloat16(c1[0] + v1.x);
        preF[tb1 + 1] = __float2bfloat16(c1[1] + v1.y);
        preF[tb1 + 2] = __float2bfloat16(c1[2] + v1.z);
        preF[tb1 + 3] = __float2bfloat16(c1[3] + v1.w);
    }
}

// ---------------- persistent recurrence kernel (2 chains per wave) ----------------
// 256 blocks x 1 wave (cooperative). Wave (bt2,jt) time-shares TWO independent
// recurrence chains: A = group bt2 and B = group bt2+8. Shared W-LDS (jt only).
// Interleave means each chain's flags are a half-step old when polled -> polls hit
// first-try, and chain A's publish latency is hidden under chain B's compute.
//
// RACE FIX (r8 post-mortem): poll and gather are both RELAXED atomics -> compiler
// may hoist the gather loads above the poll loop (LICM; no ordering requested).
// asm volatile("" ::: "memory") after the poll pins the gather issue-point after
// poll success at compile time (HW issues in program order; producer side is
// ordered by the existing vmcnt(0) fence before the flag store).
// Poll bounded: logic bug -> fast wrong answer, never a hang.
__global__ __launch_bounds__(64, 1) void lstm_persist(const short8* __restrict__ WHsw,
                                                      const __hip_bfloat16* __restrict__ preF,
                                                      __hip_bfloat16* __restrict__ h0,
                                                      __hip_bfloat16* __restrict__ h1,
                                                      __hip_bfloat16* __restrict__ S,
                                                      int* __restrict__ flags) {
    __shared__ short8 ldsB[4096];   // 64 KB: 4 gate W-tiles x 16KB, fragment order
    int wid = blockIdx.x;           // 0..255
    int btA = wid >> 5, jt = wid & 31;   // btA 0..7
    int btB = btA + 8;
    int lane = threadIdx.x;
    int li = lane & 15, q = lane >> 4;

    // stage W tiles for gates 0..3 -> LDS (linear copy of frag-order tiles)
#pragma unroll
    for (int g = 0; g < 4; ++g) {
        const char* src = (const char*)(WHsw + (size_t)(g * 32 + jt) * 1024) + lane * 16;
        char* dst = (char*)ldsB + g * 16384;
#pragma unroll
        for (int i = 0; i < 16; ++i) gload_lds16(src + i * 1024, dst + i * 1024);
    }
    // sentinel-gate W tile -> registers
    short8 b4[16];
    const short8* B4 = WHsw + (size_t)(128 + jt) * 1024 + lane;
#pragma unroll
    for (int kt = 0; kt < 16; ++kt) b4[kt] = B4[kt * 64];
    __syncthreads();   // drains vmcnt -> gload_lds data usable

    int* flagA = flags + btA * 64;        // 32 flag words per group (2 cachelines)
    int* flagB = flags + btB * 64;
    f32x4 caccA = {0.f, 0.f, 0.f, 0.f};   // c[row bt*16+li][cols jt*16+q*4..+3]
    f32x4 caccB = {0.f, 0.f, 0.f, 0.f};

    int hinA  = (btA * 16 + li) * 1024 + q * 16;
    int hinB  = (btB * 16 + li) * 1024 + q * 16;
    int houtA = (btA * 16 + li) * 1024 + (jt * 16 + q * 4) * 2;
    int houtB = (btB * 16 + li) * 1024 + (jt * 16 + q * 4) * 2;

    // preF stream: ull index = t*163840 + bt*10240 + g*2048 + jt*64 + lane
    const ull* ppwA = (const ull*)preF + ((size_t)btA * 160 + jt) * 64 + lane;
    const ull* ppwB = (const ull*)preF + ((size_t)btB * 160 + jt) * 64 + lane;

    ull ppAc[5], ppAn[5], ppBc[5], ppBn[5];
#pragma unroll
    for (int g = 0; g < 5; ++g) { ppAc[g] = ppwA[g * 2048]; ppBc[g] = ppwB[g * 2048]; }

    ull hf[32];

#define LSTM_HALF(T, FLAGP, HIN, HOUT, CACC, PPC, PPN, PPW, HC, HN)                \
  {                                                                                \
    if ((T) > 0) {                                                                 \
      int it = 0;                                                                  \
      while (true) {                                                               \
        int v = (T);                                                               \
        if (lane < 32)                                                             \
          v = __hip_atomic_load((FLAGP) + lane, __ATOMIC_RELAXED,                  \
                                __HIP_MEMORY_SCOPE_SYSTEM);                        \
        if (__all(v >= (T))) break;                                                \
        if (++it > 30000) break;   /* bounded: fail loud, never hang */            \
        __builtin_amdgcn_s_sleep(1);                                               \
      }                                                                            \
    }                                                                              \
    asm volatile("" ::: "memory");   /* pin gather AFTER poll (no relaxed hoist) */\
    const ull* hp = (const ull*)((const char*)(HC) + (HIN));                       \
    _Pragma("unroll") for (int kt = 0; kt < 16; ++kt) {                            \
      hf[2 * kt]     = __hip_atomic_load(hp + kt * 8, __ATOMIC_RELAXED,            \
                                         __HIP_MEMORY_SCOPE_SYSTEM);               \
      hf[2 * kt + 1] = __hip_atomic_load(hp + kt * 8 + 1, __ATOMIC_RELAXED,        \
                                         __HIP_MEMORY_SCOPE_SYSTEM);               \
    }                                                                              \
    if ((T) + 1 < TT) {                                                            \
      const ull* pn = (PPW) + (size_t)((T) + 1) * 163840;                          \
      _Pragma("unroll") for (int g = 0; g < 5; ++g) (PPN)[g] = pn[g * 2048];       \
    }                                                                              \
    f32x4 g0 = {0.f, 0.f, 0.f, 0.f}, g1 = g0, g2 = g0, g3 = g0, g4 = g0;           \
    _Pragma("unroll") for (int kt = 0; kt < 16; ++kt) {                            \
      U16 hv; hv.u[0] = hf[2 * kt]; hv.u[1] = hf[2 * kt + 1];                      \
      short8 bv = hv.s8;                                                           \
      g0 = MFMA16(ldsB[       kt * 64 + lane], bv, g0);                            \
      g1 = MFMA16(ldsB[1024 + kt * 64 + lane], bv, g1);                            \
      g2 = MFMA16(ldsB[2048 + kt * 64 + lane], bv, g2);                            \
      g3 = MFMA16(ldsB[3072 + kt * 64 + lane], bv, g3);                            \
      g4 = MFMA16(b4[kt], bv, g4);                                                 \
    }                                                                              \
    ull hvout = 0ull, svout = 0ull;                                                \
    _Pragma("unroll") for (int r = 0; r < 4; ++r) {                                \
      float ig = sigf(g0[r] + bf2f((short)((PPC)[0] >> (16 * r))));                \
      float fg = sigf(g1[r] + bf2f((short)((PPC)[1] >> (16 * r))));                \
      float gg = tanhf_fast(g2[r] + bf2f((short)((PPC)[2] >> (16 * r))));          \
      float og = sigf(g3[r] + bf2f((short)((PPC)[3] >> (16 * r))));                \
      float gp = sigf(g4[r] + bf2f((short)((PPC)[4] >> (16 * r))));                \
      float cn = fg * (CACC)[r] + ig * gg;                                         \
      float tc = tanhf_fast(cn);                                                   \
      (CACC)[r] = cn;                                                              \
      hvout |= ((ull)(unsigned short)f2bfs(og * tc)) << (16 * r);                  \
      svout |= ((ull)(unsigned short)f2bfs(gp * tc)) << (16 * r);                  \
    }                                                                              \
    __hip_atomic_store((ull*)((char*)(HN) + (HOUT)), hvout,                        \
                       __ATOMIC_RELAXED, __HIP_MEMORY_SCOPE_SYSTEM);               \
    *(ull*)((char*)S + (size_t)(T) * 262144 + (HOUT)) = svout;                     \
    asm volatile("s_waitcnt vmcnt(0)" ::: "memory");                               \
    if (lane == 0)                                                                 \
      __hip_atomic_store((FLAGP) + jt, (T) + 1, __ATOMIC_RELAXED,                  \
                         __HIP_MEMORY_SCOPE_SYSTEM);                               \
  }

    for (int t = 0; t < TT; t += 2) {
        LSTM_HALF(t,     flagA, hinA, houtA, caccA, ppAc, ppAn, ppwA, h0, h1);
        LSTM_HALF(t,     flagB, hinB, houtB, caccB, ppBc, ppBn, ppwB, h0, h1);
        LSTM_HALF(t + 1, flagA, hinA, houtA, caccA, ppAn, ppAc, ppwA, h1, h0);
        LSTM_HALF(t + 1, flagB, hinB, houtB, caccB, ppBn, ppBc, ppwB, h1, h0);
    }
#undef LSTM_HALF
}

// ---------------- fused output GEMM + sum-exp ----------------

__global__ __launch_bounds__(256) void lse_gemm(const short8* __restrict__ S8,
                                                const short8* __restrict__ Bsw,
                                                const float* __restrict__ ob,
                                                float* __restrict__ sumexp) {
    __shared__ short8 lds[2][1024];
    int w = threadIdx.x >> 6, lane = threadIdx.x & 63, li = lane & 15, q = lane >> 4;
    int r0 = blockIdx.x * 128 + w * 32;
    short8 a0[16], a1[16];
    const short8* Sp0 = S8 + (size_t)(r0 + li) * 64 + q;
    const short8* Sp1 = S8 + (size_t)(r0 + 16 + li) * 64 + q;
#pragma unroll
    for (int kt = 0; kt < 16; kt++) { a0[kt] = Sp0[kt * 4]; a1[kt] = Sp1[kt * 4]; }

    float s0[4] = {0.f,0.f,0.f,0.f}, s1[4] = {0.f,0.f,0.f,0.f};
    int t0 = blockIdx.y * 40;
    int t1 = t0 + 40 < NTILES ? t0 + 40 : NTILES;   // last chunk = 26

    stage_tile(Bsw + (size_t)t0 * 1024, lds[0], w, lane);
    int ib = 0;
    for (int ct = t0; ct < t1; ++ct, ib ^= 1) {
        __syncthreads();
        if (ct + 1 < t1) stage_tile(Bsw + (size_t)(ct + 1) * 1024, lds[ib ^ 1], w, lane);
        const short8* B = lds[ib];
        f32x4 c0 = {0.f,0.f,0.f,0.f}, c1 = {0.f,0.f,0.f,0.f};
#pragma unroll
        for (int kt = 0; kt < 16; kt++) {
            short8 bv = B[kt * 64 + lane];
            c0 = MFMA16(a0[kt], bv, c0);
            c1 = MFMA16(a1[kt], bv, c1);
        }
        int col = ct * 16 + li;
        if (col < NV) {
            float obv = ob[col];
#pragma unroll
            for (int r = 0; r < 4; r++) {
                s0[r] += __expf(c0[r] + obv);
                s1[r] += __expf(c1[r] + obv);
            }
        }
    }
#pragma unroll
    for (int off = 1; off < 16; off <<= 1) {
#pragma unroll
        for (int r = 0; r < 4; r++) { s0[r] += __shfl_xor(s0[r], off); s1[r] += __shfl_xor(s1[r], off); }
    }
    if (li == 0) {
#pragma unroll
        for (int r = 0; r < 4; r++) {
            atomicAdd(&sumexp[r0 + q * 4 + r], s0[r]);
            atomicAdd(&sumexp[r0 + 16 + q * 4 + r], s1[r]);
        }
    }
}

// out[row] = mask * (dot(S[row], out_W[:,tgt]) + ob[tgt] - log(sumexp[row]))
__global__ __launch_bounds__(256) void finalize_k(const __hip_bfloat16* __restrict__ S,
                                                  const __hip_bfloat16* __restrict__ Wt,
                                                  const float* __restrict__ ob,
                                                  const int* __restrict__ seqz,
                                                  const float* __restrict__ sumexp,
                                                  float* __restrict__ out) {
    int w = threadIdx.x >> 6, lane = threadIdx.x & 63;
    int row = blockIdx.x * 4 + w;        // 16384 rows, row = t*256 + b
    int t = row >> 8, b = row & 255;
    int tgt = seqz[b * TT + t];
    short8 sv = ((const short8*)(S + (size_t)row * 512))[lane];
    short8 wv = ((const short8*)(Wt + (size_t)tgt * 512))[lane];
    float d = 0.f;
#pragma unroll
    for (int i = 0; i < 8; i++) d += bf2f(sv[i]) * bf2f(wv[i]);
#pragma unroll
    for (int off = 1; off < 64; off <<= 1) d += __shfl_xor(d, off);
    if (lane == 0) {
        bool mk = (t == 0) || (seqz[b * TT + t - 1] != 0);
        out[row] = mk ? (d + ob[tgt] - logf(sumexp[row])) : 0.f;
    }
}

// ---------------- host ----------------

extern "C" void kernel_launch(void* const* d_in, const int* in_sizes, int n_in,
                              void* d_out, int out_size, void* d_ws, size_t ws_size,
                              hipStream_t stream) {
    const float* vis     = (const float*)d_in[0];
    const int*   seqz    = (const int*)d_in[1];
    const float* emb     = (const float*)d_in[2];
    const float* W_ih    = (const float*)d_in[3];
    const float* W_hh    = (const float*)d_in[4];
    const float* b_lstm  = (const float*)d_in[5];
    const float* vis2g_W = (const float*)d_in[6];
    const float* vis2g_b = (const float*)d_in[7];
    const float* w2g_W   = (const float*)d_in[8];
    const float* h2g_W   = (const float*)d_in[9];
    const float* out_W   = (const float*)d_in[10];
    const float* out_b   = (const float*)d_in[11];
    float* out = (float*)d_out;

    char* p = (char*)d_ws;
    auto carve = [&](size_t bytes) {
        void* r = (void*)p;
        p += (bytes + 255) & ~(size_t)255;
        return r;
    };
    __hip_bfloat16* WcatW = (__hip_bfloat16*)carve((size_t)NC * 512 * 2);       // [2560][512]
    __hip_bfloat16* WcatH = (__hip_bfloat16*)carve((size_t)NC * 512 * 2);       // [2560][512]
    __hip_bfloat16* visWt = (__hip_bfloat16*)carve((size_t)NC * 1024 * 2);      // [2560][1024]
    __hip_bfloat16* outWt = (__hip_bfloat16*)carve((size_t)NVP * 512 * 2);      // [10016][512]
    short8*         outSw = (short8*)carve((size_t)NTILES * 16384);             // frag order
    short8*         preBsw= (short8*)carve((size_t)160 * 16384);                // frag order
    short8*         WHsw  = (short8*)carve((size_t)160 * 16384);                // frag order
    __hip_bfloat16* visB  = (__hip_bfloat16*)carve((size_t)256 * 1024 * 2);
    float*          visC  = (float*)carve((size_t)256 * NC * 4);
    __hip_bfloat16* preF  = (__hip_bfloat16*)carve((size_t)TT * 256 * NC * 2);  // 84 MB, frag order
    __hip_bfloat16* hb0   = (__hip_bfloat16*)carve((size_t)256 * 512 * 2);
    __hip_bfloat16* hb1   = (__hip_bfloat16*)carve((size_t)256 * 512 * 2);
    __hip_bfloat16* S     = (__hip_bfloat16*)carve((size_t)TT * 256 * 512 * 2);
    float*          sume  = (float*)carve((size_t)TT * 256 * 4);
    int*            bars  = (int*)carve((size_t)16 * 64 * 4);                   // 16 groups x 32 flag words

    dim3 tb(32, 8);
    // WcatW: word -> [gates | w2g];  WcatH: h -> [gates | h2g]   (both [2560][512] = [N][K])
    transpose_cvt<<<dim3(64, 16), tb, 0, stream>>>(W_ih + 1024 * 2048, 512, 2048, 2048, WcatW, 512, 2048);
    transpose_cvt<<<dim3(16, 16), tb, 0, stream>>>(w2g_W, 512, 512, 512, WcatW + 2048 * 512, 512, 512);
    transpose_cvt<<<dim3(64, 16), tb, 0, stream>>>(W_hh, 512, 2048, 2048, WcatH, 512, 2048);
    transpose_cvt<<<dim3(16, 16), tb, 0, stream>>>(h2g_W, 512, 512, 512, WcatH + 2048 * 512, 512, 512);
    // visWt: vis -> [gates | vis2g]  [2560][1024]
    transpose_cvt<<<dim3(64, 32), tb, 0, stream>>>(W_ih, 1024, 2048, 2048, visWt, 1024, 2048);
    transpose_cvt<<<dim3(16, 32), tb, 0, stream>>>(vis2g_W, 1024, 512, 512, visWt + 2048 * 1024, 1024, 512);
    // out_W transposed, zero-padded to 10016 rows
    transpose_cvt<<<dim3(313, 16), tb, 0, stream>>>(out_W, 512, NV, NV, outWt, 512, NVP);
    // fragment-order swizzles
    swizzle_frag<<<2504, 256, 0, stream>>>((const short8*)outWt, outSw, NTILES);
    swizzle_frag<<<640, 256, 0, stream>>>((const short8*)WcatW, preBsw, 160);
    swizzle_frag<<<640, 256, 0, stream>>>((const short8*)WcatH, WHsw, 160);

    // h0 = zeros (step-0 input, r7-verified memset visibility); flags = 0; sumexp = 0
    hipMemsetAsync(hb0, 0, (size_t)256 * 512 * 2, stream);
    hipMemsetAsync(bars, 0, (size_t)16 * 64 * 4, stream);
    hipMemsetAsync(sume, 0, (size_t)TT * 256 * 4, stream);

    cvt_vis<<<1024, 256, 0, stream>>>(vis, visB);
    gemm_vis<<<640, 256, 0, stream>>>(visB, visWt, b_lstm, vis2g_b, visC);
    pre_gemm<<<dim3(128, 8), 256, 0, stream>>>(seqz, emb, preBsw, visC, preF);

    // all 64 recurrence steps in one cooperative persistent kernel (2 chains/wave)
    {
        const short8* WHsw_c = (const short8*)WHsw;
        const __hip_bfloat16* preF_c = (const __hip_bfloat16*)preF;
        __hip_bfloat16* h0a = hb0;
        __hip_bfloat16* h1a = hb1;
        __hip_bfloat16* Sa = S;
        int* barsa = bars;
        void* kargs[6] = { &WHsw_c, &preF_c, &h0a, &h1a, &Sa, &barsa };
        hipLaunchCooperativeKernel((void*)lstm_persist, dim3(256), dim3(64), kargs, 0, stream);
    }

    lse_gemm<<<dim3(128, 16), 256, 0, stream>>>((const short8*)S, outSw, out_b, sume);
    finalize_k<<<4096, 256, 0, stream>>>(S, outWt, out_b, seqz, sume, out);
}

// Round 10
// 802.161 us; speedup vs baseline: 1.1263x; 1.0067x over previous
//
#include <hip/hip_runtime.h>
#include <hip/hip_bf16.h>
#include <math.h>

typedef __attribute__((ext_vector_type(8))) short short8;
typedef __attribute__((ext_vector_type(4))) float f32x4;

#define MFMA16(a, b, c) __builtin_amdgcn_mfma_f32_16x16x32_bf16((a), (b), (c), 0, 0, 0)

#define BB 256
#define TT 64
#define VOCAB 10000
#define WORD 512
#define RNN 512
#define NC 2560          /* 2048 gates + 512 sentinel-gate pre */
#define NV 10001
#define NVP 10016
#define NTILES 626       /* NVP/16 */

typedef unsigned long long ull;
union U16 { ull u[2]; short8 s8; };

// fast transcendentals (r7-verified: absmax 0.0625, same as libm path)
__device__ __forceinline__ float sigf(float x) {
    return __builtin_amdgcn_rcpf(1.f + __expf(-x));
}
__device__ __forceinline__ float tanhf_fast(float x) {
    // 1 - 2/(e^{2x}+1); saturates correctly at +-1
    return 1.f - 2.f * __builtin_amdgcn_rcpf(__expf(2.f * x) + 1.f);
}
__device__ __forceinline__ float bf2f(short s) {
    union { unsigned int u; float f; } v;
    v.u = ((unsigned int)(unsigned short)s) << 16;
    return v.f;
}
__device__ __forceinline__ short f2bfs(float x) {
    __hip_bfloat16 h = __float2bfloat16(x);
    return *reinterpret_cast<short*>(&h);
}

// async global->LDS, 16B per lane. lds dest = wave-uniform base + lane*16 (HW rule).
__device__ __forceinline__ void gload_lds16(const void* g, void* l) {
    __builtin_amdgcn_global_load_lds((const __attribute__((address_space(1))) void*)g,
                                     (__attribute__((address_space(3))) void*)l, 16, 0, 0);
}

// stage one 16KB fragment-order tile: 4 waves x 4KB each
__device__ __forceinline__ void stage_tile(const short8* gsrc, void* lbuf, int w, int lane) {
    const char* g = (const char*)gsrc + w * 4096 + lane * 16;
    char* l = (char*)lbuf + w * 4096;
#pragma unroll
    for (int i = 0; i < 4; i++) gload_lds16(g + i * 1024, l + i * 1024);
}

// ---------------- prep kernels ----------------

// dst[n][k] = (float->bf16) src[k][n]; zero-fill for n in [N, dstN)
__global__ void transpose_cvt(const float* __restrict__ src, int K, int N, int ld,
                              __hip_bfloat16* __restrict__ dst, int dst_ld, int dstN) {
    __shared__ float tile[32][33];
    int k0 = blockIdx.y * 32, n0 = blockIdx.x * 32;
    int tx = threadIdx.x, ty = threadIdx.y;   // 32 x 8
#pragma unroll
    for (int i = 0; i < 32; i += 8) {
        int k = k0 + ty + i, n = n0 + tx;
        tile[ty + i][tx] = (k < K && n < N) ? src[(size_t)k * ld + n] : 0.f;
    }
    __syncthreads();
#pragma unroll
    for (int i = 0; i < 32; i += 8) {
        int n = n0 + ty + i, k = k0 + tx;
        if (n < dstN && k < K) dst[(size_t)n * dst_ld + k] = __float2bfloat16(tile[tx][ty + i]);
    }
}

// [ntiles*16][512] ([N][K]) -> fragment order: dst[ct][kt][lane] = src[(ct*16+(l&15))][kt*32+(l>>4)*8 ..+7]
__global__ void swizzle_frag(const short8* __restrict__ src, short8* __restrict__ dst, int ntiles) {
    int t = blockIdx.x * 256 + threadIdx.x;
    if (t >= ntiles * 1024) return;
    int ct = t >> 10, r = t & 1023, kt = r >> 6, l = r & 63;
    int li = l & 15, q = l >> 4;
    dst[t] = src[(size_t)(ct * 16 + li) * 64 + kt * 4 + q];
}

__global__ void cvt_vis(const float* __restrict__ v, __hip_bfloat16* __restrict__ d) {
    int idx = blockIdx.x * 256 + threadIdx.x;   // 262144
    d[idx] = __float2bfloat16(v[idx]);
}

// visC[256][2560] = vis_bf16 @ visW + bias (b_lstm for n<2048 else vis2g_b)
__global__ __launch_bounds__(256) void gemm_vis(const __hip_bfloat16* __restrict__ A,
                                                const __hip_bfloat16* __restrict__ Bt,
                                                const float* __restrict__ b_lstm,
                                                const float* __restrict__ vis2g_b,
                                                float* __restrict__ C) {
    int wid = blockIdx.x * 4 + (threadIdx.x >> 6);   // 2560 waves: 16 x 160 tiles
    int mt = wid / 160, nt = wid % 160;
    int lane = threadIdx.x & 63, li = lane & 15, q = lane >> 4;
    const short8* Ap = (const short8*)A + (mt * 16 + li) * 128 + q;   // ld 1024 -> 128 chunks
    const short8* Bp = (const short8*)Bt + (nt * 16 + li) * 128 + q;
    f32x4 acc = {0.f, 0.f, 0.f, 0.f};
#pragma unroll
    for (int kk = 0; kk < 128; kk += 4) acc = MFMA16(Ap[kk], Bp[kk], acc);
    int col = nt * 16 + li;
    float bias = (col < 2048) ? b_lstm[col] : vis2g_b[col - 2048];
#pragma unroll
    for (int r = 0; r < 4; r++) {
        int row = mt * 16 + q * 4 + r;
        C[row * NC + col] = acc[r] + bias;
    }
}

// preF in TRANSPOSED-fragment order: preF[((rowtile*160 + ct)*256 + lane*4) + r]
//   = pre[row = rowtile*16 + (lane&15)][col = ct*16 + (lane>>4)*4 + r]
__global__ __launch_bounds__(256) void pre_gemm(const int* __restrict__ seqz,
                                                const float* __restrict__ emb,
                                                const short8* __restrict__ Bsw,   // 160 tiles, frag order
                                                const float* __restrict__ visC,
                                                __hip_bfloat16* __restrict__ preF) {
    __shared__ short8 lds[2][1024];
    int w = threadIdx.x >> 6, lane = threadIdx.x & 63, li = lane & 15, q = lane >> 4;
    int r0 = blockIdx.x * 128 + w * 32;

    short8 a0[16], a1[16];
    {
        int row = r0 + li;
        int t = row >> 8, b = row & 255;
        int wid_ = (t == 0) ? (VOCAB + 1) : seqz[b * TT + (t - 1)];
        const float* er = emb + (size_t)wid_ * WORD + q * 8;
#pragma unroll
        for (int kt = 0; kt < 16; kt++) {
            float4 f0 = ((const float4*)(er + kt * 32))[0];
            float4 f1 = ((const float4*)(er + kt * 32))[1];
            short8 v; v[0]=f2bfs(f0.x); v[1]=f2bfs(f0.y); v[2]=f2bfs(f0.z); v[3]=f2bfs(f0.w);
            v[4]=f2bfs(f1.x); v[5]=f2bfs(f1.y); v[6]=f2bfs(f1.z); v[7]=f2bfs(f1.w);
            a0[kt] = v;
        }
        row = r0 + 16 + li; t = row >> 8; b = row & 255;
        wid_ = (t == 0) ? (VOCAB + 1) : seqz[b * TT + (t - 1)];
        er = emb + (size_t)wid_ * WORD + q * 8;
#pragma unroll
        for (int kt = 0; kt < 16; kt++) {
            float4 f0 = ((const float4*)(er + kt * 32))[0];
            float4 f1 = ((const float4*)(er + kt * 32))[1];
            short8 v; v[0]=f2bfs(f0.x); v[1]=f2bfs(f0.y); v[2]=f2bfs(f0.z); v[3]=f2bfs(f0.w);
            v[4]=f2bfs(f1.x); v[5]=f2bfs(f1.y); v[6]=f2bfs(f1.z); v[7]=f2bfs(f1.w);
            a1[kt] = v;
        }
    }

    int t0 = blockIdx.y * 20, t1 = t0 + 20;   // 8 chunks x 20 = 160
    stage_tile(Bsw + (size_t)t0 * 1024, lds[0], w, lane);
    int ib = 0;
    for (int ct = t0; ct < t1; ++ct, ib ^= 1) {
        __syncthreads();
        if (ct + 1 < t1) stage_tile(Bsw + (size_t)(ct + 1) * 1024, lds[ib ^ 1], w, lane);
        const short8* B = lds[ib];
        f32x4 c0 = {0.f,0.f,0.f,0.f}, c1 = {0.f,0.f,0.f,0.f};
#pragma unroll
        for (int kt = 0; kt < 16; kt++) {
            short8 bv = B[kt * 64 + lane];
            // TRANSPOSED: A = W-frag, B = emb-frag -> lane holds batch row li, gate cols ct*16+q*4..+3
            c0 = MFMA16(bv, a0[kt], c0);
            c1 = MFMA16(bv, a1[kt], c1);
        }
        int col0 = ct * 16 + q * 4;
        size_t tb0 = ((size_t)(r0 >> 4) * 160 + ct) * 256 + lane * 4;
        size_t tb1 = tb0 + (size_t)160 * 256;
        float4 v0 = *(const float4*)(visC + ((r0 + li) & 255) * NC + col0);
        float4 v1 = *(const float4*)(visC + ((r0 + 16 + li) & 255) * NC + col0);
        preF[tb0 + 0] = __float2bfloat16(c0[0] + v0.x);
        preF[tb0 + 1] = __float2bfloat16(c0[1] + v0.y);
        preF[tb0 + 2] = __float2bfloat16(c0[2] + v0.z);
        preF[tb0 + 3] = __float2bfloat16(c0[3] + v0.w);
        preF[tb1 + 0] = __float2bfloat16(c1[0] + v1.x);
        preF[tb1 + 1] = __float2bfloat16(c1[1] + v1.y);
        preF[tb1 + 2] = __float2bfloat16(c1[2] + v1.z);
        preF[tb1 + 3] = __float2bfloat16(c1[3] + v1.w);
    }
}

// ---------------- persistent recurrence kernel (2 chains, rotated pipeline) ----------------
// 256 blocks x 1 wave (cooperative). Wave (btA,jt) time-shares chains A=btA, B=btA+8.
// r9 post-mortem: per-half cost = poll + gather + compute + EXPOSED store-drain. This
// round rotates the pipeline: each phase drains the OTHER chain's stores inside its own
// poll window (one overlapped RTT), then publishes the other chain's flag, then computes.
//   PHASE(X,T): issue poll-load X-flags -> vmcnt(0) (drains Y stores + poll together)
//               -> flag-store Y (data provably drained) -> eval/retry poll
//               -> fence -> gather X -> prefetch -> MFMA -> epilogue -> store h,S (no drain)
// Invariants preserved: flag only after data drained (explicit vmcnt(0) precedes it);
// gather only after poll success (compiler fence, r8 race fix). Flags are one
// compute-phase old when polled -> first-try hits. Poll bounded: never hangs.
__global__ __launch_bounds__(64, 1) void lstm_persist(const short8* __restrict__ WHsw,
                                                      const __hip_bfloat16* __restrict__ preF,
                                                      __hip_bfloat16* __restrict__ h0,
                                                      __hip_bfloat16* __restrict__ h1,
                                                      __hip_bfloat16* __restrict__ S,
                                                      int* __restrict__ flags) {
    __shared__ short8 ldsB[4096];   // 64 KB: 4 gate W-tiles x 16KB, fragment order
    int wid = blockIdx.x;           // 0..255
    int btA = wid >> 5, jt = wid & 31;   // btA 0..7
    int btB = btA + 8;
    int lane = threadIdx.x;
    int li = lane & 15, q = lane >> 4;

    // stage W tiles for gates 0..3 -> LDS (linear copy of frag-order tiles)
#pragma unroll
    for (int g = 0; g < 4; ++g) {
        const char* src = (const char*)(WHsw + (size_t)(g * 32 + jt) * 1024) + lane * 16;
        char* dst = (char*)ldsB + g * 16384;
#pragma unroll
        for (int i = 0; i < 16; ++i) gload_lds16(src + i * 1024, dst + i * 1024);
    }
    // sentinel-gate W tile -> registers
    short8 b4[16];
    const short8* B4 = WHsw + (size_t)(128 + jt) * 1024 + lane;
#pragma unroll
    for (int kt = 0; kt < 16; ++kt) b4[kt] = B4[kt * 64];
    __syncthreads();   // drains vmcnt -> gload_lds data usable

    int* flagA = flags + btA * 64;        // 32 flag words per group (2 cachelines)
    int* flagB = flags + btB * 64;
    f32x4 caccA = {0.f, 0.f, 0.f, 0.f};   // c[row bt*16+li][cols jt*16+q*4..+3]
    f32x4 caccB = {0.f, 0.f, 0.f, 0.f};

    int hinA  = (btA * 16 + li) * 1024 + q * 16;
    int hinB  = (btB * 16 + li) * 1024 + q * 16;
    int houtA = (btA * 16 + li) * 1024 + (jt * 16 + q * 4) * 2;
    int houtB = (btB * 16 + li) * 1024 + (jt * 16 + q * 4) * 2;

    // preF stream: ull index = t*163840 + bt*10240 + g*2048 + jt*64 + lane
    const ull* ppwA = (const ull*)preF + ((size_t)btA * 160 + jt) * 64 + lane;
    const ull* ppwB = (const ull*)preF + ((size_t)btB * 160 + jt) * 64 + lane;

    ull ppAc[5], ppAn[5], ppBc[5], ppBn[5];
#pragma unroll
    for (int g = 0; g < 5; ++g) { ppAc[g] = ppwA[g * 2048]; ppBc[g] = ppwB[g * 2048]; }

    ull hf[32];

// PHASE: sync (poll this chain, drain+flag the other chain) then compute this chain.
//   T      : step for THIS chain (poll target, gather source h, store dest)
//   POLLP  : this chain's flag array;   DOPOLL: whether to poll (t>0)
//   FLAGP/FV/DOFLAG : other chain's flag array / value to publish / enable
#define PHASE(T, POLLP, DOPOLL, FLAGP, FV, DOFLAG, HIN, HOUT, CACC, PPC, PPN, PPW, HC, HN) \
  {                                                                                \
    int v = (T);                                                                   \
    if (DOPOLL) {                                                                  \
      if (lane < 32)                                                               \
        v = __hip_atomic_load((POLLP) + lane, __ATOMIC_RELAXED,                    \
                              __HIP_MEMORY_SCOPE_SYSTEM);                          \
    }                                                                              \
    asm volatile("s_waitcnt vmcnt(0)" ::: "memory");  /* drain other-chain stores  \
                                                         + poll load, overlapped */\
    if ((DOFLAG) && lane == 0)                                                     \
      __hip_atomic_store((FLAGP) + jt, (FV), __ATOMIC_RELAXED,                     \
                         __HIP_MEMORY_SCOPE_SYSTEM);                               \
    if (DOPOLL) {                                                                  \
      int it = 0;                                                                  \
      while (!__all(v >= (T))) {                                                   \
        if (++it > 30000) break;   /* bounded: fail loud, never hang */            \
        __builtin_amdgcn_s_sleep(1);                                               \
        if (lane < 32)                                                             \
          v = __hip_atomic_load((POLLP) + lane, __ATOMIC_RELAXED,                  \
                                __HIP_MEMORY_SCOPE_SYSTEM);                        \
      }                                                                            \
    }                                                                              \
    asm volatile("" ::: "memory");   /* pin gather AFTER poll (r8 race fix) */     \
    const ull* hp = (const ull*)((const char*)(HC) + (HIN));                       \
    _Pragma("unroll") for (int kt = 0; kt < 16; ++kt) {                            \
      hf[2 * kt]     = __hip_atomic_load(hp + kt * 8, __ATOMIC_RELAXED,            \
                                         __HIP_MEMORY_SCOPE_SYSTEM);               \
      hf[2 * kt + 1] = __hip_atomic_load(hp + kt * 8 + 1, __ATOMIC_RELAXED,        \
                                         __HIP_MEMORY_SCOPE_SYSTEM);               \
    }                                                                              \
    if ((T) + 1 < TT) {                                                            \
      const ull* pn = (PPW) + (size_t)((T) + 1) * 163840;                          \
      _Pragma("unroll") for (int g = 0; g < 5; ++g) (PPN)[g] = pn[g * 2048];       \
    }                                                                              \
    f32x4 g0 = {0.f, 0.f, 0.f, 0.f}, g1 = g0, g2 = g0, g3 = g0, g4 = g0;           \
    _Pragma("unroll") for (int kt = 0; kt < 16; ++kt) {                            \
      U16 hv; hv.u[0] = hf[2 * kt]; hv.u[1] = hf[2 * kt + 1];                      \
      short8 bv = hv.s8;                                                           \
      g0 = MFMA16(ldsB[       kt * 64 + lane], bv, g0);                            \
      g1 = MFMA16(ldsB[1024 + kt * 64 + lane], bv, g1);                            \
      g2 = MFMA16(ldsB[2048 + kt * 64 + lane], bv, g2);                            \
      g3 = MFMA16(ldsB[3072 + kt * 64 + lane], bv, g3);                            \
      g4 = MFMA16(b4[kt], bv, g4);                                                 \
    }                                                                              \
    ull hvout = 0ull, svout = 0ull;                                                \
    _Pragma("unroll") for (int r = 0; r < 4; ++r) {                                \
      float ig = sigf(g0[r] + bf2f((short)((PPC)[0] >> (16 * r))));                \
      float fg = sigf(g1[r] + bf2f((short)((PPC)[1] >> (16 * r))));                \
      float gg = tanhf_fast(g2[r] + bf2f((short)((PPC)[2] >> (16 * r))));          \
      float og = sigf(g3[r] + bf2f((short)((PPC)[3] >> (16 * r))));                \
      float gp = sigf(g4[r] + bf2f((short)((PPC)[4] >> (16 * r))));                \
      float cn = fg * (CACC)[r] + ig * gg;                                         \
      float tc = tanhf_fast(cn);                                                   \
      (CACC)[r] = cn;                                                              \
      hvout |= ((ull)(unsigned short)f2bfs(og * tc)) << (16 * r);                  \
      svout |= ((ull)(unsigned short)f2bfs(gp * tc)) << (16 * r);                  \
    }                                                                              \
    __hip_atomic_store((ull*)((char*)(HN) + (HOUT)), hvout,                        \
                       __ATOMIC_RELAXED, __HIP_MEMORY_SCOPE_SYSTEM);               \
    *(ull*)((char*)S + (size_t)(T) * 262144 + (HOUT)) = svout;                     \
    /* no drain here: next phase's poll window absorbs it */                       \
  }

    // Phase schedule (t even): PA(t) polls A>=t, publishes flagB=t (B's t-1 done).
    //                          PB(t) polls B>=t, publishes flagA=t+1 (A's t done).
    for (int t = 0; t < TT; t += 2) {
        PHASE(t,     flagA, (t > 0), flagB, t,     (t > 0), hinA, houtA, caccA, ppAc, ppAn, ppwA, h0, h1);
        PHASE(t,     flagB, (t > 0), flagA, t + 1, true,    hinB, houtB, caccB, ppBc, ppBn, ppwB, h0, h1);
        PHASE(t + 1, flagA, true,    flagB, t + 1, true,    hinA, houtA, caccA, ppAn, ppAc, ppwA, h1, h0);
        PHASE(t + 1, flagB, true,    flagA, t + 2, true,    hinB, houtB, caccB, ppBn, ppBc, ppwB, h1, h0);
    }
#undef PHASE
}

// ---------------- fused output GEMM + sum-exp ----------------

__global__ __launch_bounds__(256) void lse_gemm(const short8* __restrict__ S8,
                                                const short8* __restrict__ Bsw,
                                                const float* __restrict__ ob,
                                                float* __restrict__ sumexp) {
    __shared__ short8 lds[2][1024];
    int w = threadIdx.x >> 6, lane = threadIdx.x & 63, li = lane & 15, q = lane >> 4;
    int r0 = blockIdx.x * 128 + w * 32;
    short8 a0[16], a1[16];
    const short8* Sp0 = S8 + (size_t)(r0 + li) * 64 + q;
    const short8* Sp1 = S8 + (size_t)(r0 + 16 + li) * 64 + q;
#pragma unroll
    for (int kt = 0; kt < 16; kt++) { a0[kt] = Sp0[kt * 4]; a1[kt] = Sp1[kt * 4]; }

    float s0[4] = {0.f,0.f,0.f,0.f}, s1[4] = {0.f,0.f,0.f,0.f};
    int t0 = blockIdx.y * 40;
    int t1 = t0 + 40 < NTILES ? t0 + 40 : NTILES;   // last chunk = 26

    stage_tile(Bsw + (size_t)t0 * 1024, lds[0], w, lane);
    int ib = 0;
    for (int ct = t0; ct < t1; ++ct, ib ^= 1) {
        __syncthreads();
        if (ct + 1 < t1) stage_tile(Bsw + (size_t)(ct + 1) * 1024, lds[ib ^ 1], w, lane);
        const short8* B = lds[ib];
        f32x4 c0 = {0.f,0.f,0.f,0.f}, c1 = {0.f,0.f,0.f,0.f};
#pragma unroll
        for (int kt = 0; kt < 16; kt++) {
            short8 bv = B[kt * 64 + lane];
            c0 = MFMA16(a0[kt], bv, c0);
            c1 = MFMA16(a1[kt], bv, c1);
        }
        int col = ct * 16 + li;
        if (col < NV) {
            float obv = ob[col];
#pragma unroll
            for (int r = 0; r < 4; r++) {
                s0[r] += __expf(c0[r] + obv);
                s1[r] += __expf(c1[r] + obv);
            }
        }
    }
#pragma unroll
    for (int off = 1; off < 16; off <<= 1) {
#pragma unroll
        for (int r = 0; r < 4; r++) { s0[r] += __shfl_xor(s0[r], off); s1[r] += __shfl_xor(s1[r], off); }
    }
    if (li == 0) {
#pragma unroll
        for (int r = 0; r < 4; r++) {
            atomicAdd(&sumexp[r0 + q * 4 + r], s0[r]);
            atomicAdd(&sumexp[r0 + 16 + q * 4 + r], s1[r]);
        }
    }
}

// out[row] = mask * (dot(S[row], out_W[:,tgt]) + ob[tgt] - log(sumexp[row]))
__global__ __launch_bounds__(256) void finalize_k(const __hip_bfloat16* __restrict__ S,
                                                  const __hip_bfloat16* __restrict__ Wt,
                                                  const float* __restrict__ ob,
                                                  const int* __restrict__ seqz,
                                                  const float* __restrict__ sumexp,
                                                  float* __restrict__ out) {
    int w = threadIdx.x >> 6, lane = threadIdx.x & 63;
    int row = blockIdx.x * 4 + w;        // 16384 rows, row = t*256 + b
    int t = row >> 8, b = row & 255;
    int tgt = seqz[b * TT + t];
    short8 sv = ((const short8*)(S + (size_t)row * 512))[lane];
    short8 wv = ((const short8*)(Wt + (size_t)tgt * 512))[lane];
    float d = 0.f;
#pragma unroll
    for (int i = 0; i < 8; i++) d += bf2f(sv[i]) * bf2f(wv[i]);
#pragma unroll
    for (int off = 1; off < 64; off <<= 1) d += __shfl_xor(d, off);
    if (lane == 0) {
        bool mk = (t == 0) || (seqz[b * TT + t - 1] != 0);
        out[row] = mk ? (d + ob[tgt] - logf(sumexp[row])) : 0.f;
    }
}

// ---------------- host ----------------

extern "C" void kernel_launch(void* const* d_in, const int* in_sizes, int n_in,
                              void* d_out, int out_size, void* d_ws, size_t ws_size,
                              hipStream_t stream) {
    const float* vis     = (const float*)d_in[0];
    const int*   seqz    = (const int*)d_in[1];
    const float* emb     = (const float*)d_in[2];
    const float* W_ih    = (const float*)d_in[3];
    const float* W_hh    = (const float*)d_in[4];
    const float* b_lstm  = (const float*)d_in[5];
    const float* vis2g_W = (const float*)d_in[6];
    const float* vis2g_b = (const float*)d_in[7];
    const float* w2g_W   = (const float*)d_in[8];
    const float* h2g_W   = (const float*)d_in[9];
    const float* out_W   = (const float*)d_in[10];
    const float* out_b   = (const float*)d_in[11];
    float* out = (float*)d_out;

    char* p = (char*)d_ws;
    auto carve = [&](size_t bytes) {
        void* r = (void*)p;
        p += (bytes + 255) & ~(size_t)255;
        return r;
    };
    __hip_bfloat16* WcatW = (__hip_bfloat16*)carve((size_t)NC * 512 * 2);       // [2560][512]
    __hip_bfloat16* WcatH = (__hip_bfloat16*)carve((size_t)NC * 512 * 2);       // [2560][512]
    __hip_bfloat16* visWt = (__hip_bfloat16*)carve((size_t)NC * 1024 * 2);      // [2560][1024]
    __hip_bfloat16* outWt = (__hip_bfloat16*)carve((size_t)NVP * 512 * 2);      // [10016][512]
    short8*         outSw = (short8*)carve((size_t)NTILES * 16384);             // frag order
    short8*         preBsw= (short8*)carve((size_t)160 * 16384);                // frag order
    short8*         WHsw  = (short8*)carve((size_t)160 * 16384);                // frag order
    __hip_bfloat16* visB  = (__hip_bfloat16*)carve((size_t)256 * 1024 * 2);
    float*          visC  = (float*)carve((size_t)256 * NC * 4);
    __hip_bfloat16* preF  = (__hip_bfloat16*)carve((size_t)TT * 256 * NC * 2);  // 84 MB, frag order
    __hip_bfloat16* hb0   = (__hip_bfloat16*)carve((size_t)256 * 512 * 2);
    __hip_bfloat16* hb1   = (__hip_bfloat16*)carve((size_t)256 * 512 * 2);
    __hip_bfloat16* S     = (__hip_bfloat16*)carve((size_t)TT * 256 * 512 * 2);
    float*          sume  = (float*)carve((size_t)TT * 256 * 4);
    int*            bars  = (int*)carve((size_t)16 * 64 * 4);                   // 16 groups x 32 flag words

    dim3 tb(32, 8);
    // WcatW: word -> [gates | w2g];  WcatH: h -> [gates | h2g]   (both [2560][512] = [N][K])
    transpose_cvt<<<dim3(64, 16), tb, 0, stream>>>(W_ih + 1024 * 2048, 512, 2048, 2048, WcatW, 512, 2048);
    transpose_cvt<<<dim3(16, 16), tb, 0, stream>>>(w2g_W, 512, 512, 512, WcatW + 2048 * 512, 512, 512);
    transpose_cvt<<<dim3(64, 16), tb, 0, stream>>>(W_hh, 512, 2048, 2048, WcatH, 512, 2048);
    transpose_cvt<<<dim3(16, 16), tb, 0, stream>>>(h2g_W, 512, 512, 512, WcatH + 2048 * 512, 512, 512);
    // visWt: vis -> [gates | vis2g]  [2560][1024]
    transpose_cvt<<<dim3(64, 32), tb, 0, stream>>>(W_ih, 1024, 2048, 2048, visWt, 1024, 2048);
    transpose_cvt<<<dim3(16, 32), tb, 0, stream>>>(vis2g_W, 1024, 512, 512, visWt + 2048 * 1024, 1024, 512);
    // out_W transposed, zero-padded to 10016 rows
    transpose_cvt<<<dim3(313, 16), tb, 0, stream>>>(out_W, 512, NV, NV, outWt, 512, NVP);
    // fragment-order swizzles
    swizzle_frag<<<2504, 256, 0, stream>>>((const short8*)outWt, outSw, NTILES);
    swizzle_frag<<<640, 256, 0, stream>>>((const short8*)WcatW, preBsw, 160);
    swizzle_frag<<<640, 256, 0, stream>>>((const short8*)WcatH, WHsw, 160);

    // h0 = zeros (step-0 input); flags = 0; sumexp = 0
    hipMemsetAsync(hb0, 0, (size_t)256 * 512 * 2, stream);
    hipMemsetAsync(bars, 0, (size_t)16 * 64 * 4, stream);
    hipMemsetAsync(sume, 0, (size_t)TT * 256 * 4, stream);

    cvt_vis<<<1024, 256, 0, stream>>>(vis, visB);
    gemm_vis<<<640, 256, 0, stream>>>(visB, visWt, b_lstm, vis2g_b, visC);
    pre_gemm<<<dim3(128, 8), 256, 0, stream>>>(seqz, emb, preBsw, visC, preF);

    // all 64 recurrence steps in one cooperative persistent kernel (2 chains/wave)
    {
        const short8* WHsw_c = (const short8*)WHsw;
        const __hip_bfloat16* preF_c = (const __hip_bfloat16*)preF;
        __hip_bfloat16* h0a = hb0;
        __hip_bfloat16* h1a = hb1;
        __hip_bfloat16* Sa = S;
        int* barsa = bars;
        void* kargs[6] = { &WHsw_c, &preF_c, &h0a, &h1a, &Sa, &barsa };
        hipLaunchCooperativeKernel((void*)lstm_persist, dim3(256), dim3(64), kargs, 0, stream);
    }

    lse_gemm<<<dim3(128, 16), 256, 0, stream>>>((const short8*)S, outSw, out_b, sume);
    finalize_k<<<4096, 256, 0, stream>>>(S, outWt, out_b, seqz, sume, out);
}

// Round 11
// 750.062 us; speedup vs baseline: 1.2045x; 1.0695x over previous
//
#include <hip/hip_runtime.h>
#include <hip/hip_bf16.h>
#include <math.h>

typedef __attribute__((ext_vector_type(8))) short short8;
typedef __attribute__((ext_vector_type(4))) float f32x4;

#define MFMA16(a, b, c) __builtin_amdgcn_mfma_f32_16x16x32_bf16((a), (b), (c), 0, 0, 0)

#define BB 256
#define TT 64
#define VOCAB 10000
#define WORD 512
#define RNN 512
#define NC 2560          /* 2048 gates + 512 sentinel-gate pre */
#define NV 10001
#define NVP 10016
#define NTILES 626       /* NVP/16 */

typedef unsigned long long ull;
union U16 { ull u[2]; short8 s8; };

// fast transcendentals (r7-verified: absmax 0.0625, same as libm path)
__device__ __forceinline__ float sigf(float x) {
    return __builtin_amdgcn_rcpf(1.f + __expf(-x));
}
__device__ __forceinline__ float tanhf_fast(float x) {
    // 1 - 2/(e^{2x}+1); saturates correctly at +-1
    return 1.f - 2.f * __builtin_amdgcn_rcpf(__expf(2.f * x) + 1.f);
}
__device__ __forceinline__ float bf2f(short s) {
    union { unsigned int u; float f; } v;
    v.u = ((unsigned int)(unsigned short)s) << 16;
    return v.f;
}
__device__ __forceinline__ short f2bfs(float x) {
    __hip_bfloat16 h = __float2bfloat16(x);
    return *reinterpret_cast<short*>(&h);
}

// async global->LDS, 16B per lane. lds dest = wave-uniform base + lane*16 (HW rule).
__device__ __forceinline__ void gload_lds16(const void* g, void* l) {
    __builtin_amdgcn_global_load_lds((const __attribute__((address_space(1))) void*)g,
                                     (__attribute__((address_space(3))) void*)l, 16, 0, 0);
}

// stage one 16KB fragment-order tile: 4 waves x 4KB each
__device__ __forceinline__ void stage_tile(const short8* gsrc, void* lbuf, int w, int lane) {
    const char* g = (const char*)gsrc + w * 4096 + lane * 16;
    char* l = (char*)lbuf + w * 4096;
#pragma unroll
    for (int i = 0; i < 4; i++) gload_lds16(g + i * 1024, l + i * 1024);
}

// ---------------- prep kernels ----------------

// dst[n][k] = (float->bf16) src[k][n]; zero-fill for n in [N, dstN)
__global__ void transpose_cvt(const float* __restrict__ src, int K, int N, int ld,
                              __hip_bfloat16* __restrict__ dst, int dst_ld, int dstN) {
    __shared__ float tile[32][33];
    int k0 = blockIdx.y * 32, n0 = blockIdx.x * 32;
    int tx = threadIdx.x, ty = threadIdx.y;   // 32 x 8
#pragma unroll
    for (int i = 0; i < 32; i += 8) {
        int k = k0 + ty + i, n = n0 + tx;
        tile[ty + i][tx] = (k < K && n < N) ? src[(size_t)k * ld + n] : 0.f;
    }
    __syncthreads();
#pragma unroll
    for (int i = 0; i < 32; i += 8) {
        int n = n0 + ty + i, k = k0 + tx;
        if (n < dstN && k < K) dst[(size_t)n * dst_ld + k] = __float2bfloat16(tile[tx][ty + i]);
    }
}

// [ntiles*16][512] ([N][K]) -> fragment order: dst[ct][kt][lane] = src[(ct*16+(l&15))][kt*32+(l>>4)*8 ..+7]
__global__ void swizzle_frag(const short8* __restrict__ src, short8* __restrict__ dst, int ntiles) {
    int t = blockIdx.x * 256 + threadIdx.x;
    if (t >= ntiles * 1024) return;
    int ct = t >> 10, r = t & 1023, kt = r >> 6, l = r & 63;
    int li = l & 15, q = l >> 4;
    dst[t] = src[(size_t)(ct * 16 + li) * 64 + kt * 4 + q];
}

__global__ void cvt_vis(const float* __restrict__ v, __hip_bfloat16* __restrict__ d) {
    int idx = blockIdx.x * 256 + threadIdx.x;   // 262144
    d[idx] = __float2bfloat16(v[idx]);
}

// emb fp32 -> bf16, row-major [10002][512] (8 elems/thread)
__global__ void cvt_emb(const float* __restrict__ e, short8* __restrict__ d, int n8) {
    int idx = blockIdx.x * 256 + threadIdx.x;
    if (idx >= n8) return;
    const float4* s = (const float4*)e + (size_t)idx * 2;
    float4 f0 = s[0], f1 = s[1];
    short8 v;
    v[0]=f2bfs(f0.x); v[1]=f2bfs(f0.y); v[2]=f2bfs(f0.z); v[3]=f2bfs(f0.w);
    v[4]=f2bfs(f1.x); v[5]=f2bfs(f1.y); v[6]=f2bfs(f1.z); v[7]=f2bfs(f1.w);
    d[idx] = v;
}

// visC[256][2560] = vis_bf16 @ visW + bias (b_lstm for n<2048 else vis2g_b)
__global__ __launch_bounds__(256) void gemm_vis(const __hip_bfloat16* __restrict__ A,
                                                const __hip_bfloat16* __restrict__ Bt,
                                                const float* __restrict__ b_lstm,
                                                const float* __restrict__ vis2g_b,
                                                float* __restrict__ C) {
    int wid = blockIdx.x * 4 + (threadIdx.x >> 6);   // 2560 waves: 16 x 160 tiles
    int mt = wid / 160, nt = wid % 160;
    int lane = threadIdx.x & 63, li = lane & 15, q = lane >> 4;
    const short8* Ap = (const short8*)A + (mt * 16 + li) * 128 + q;   // ld 1024 -> 128 chunks
    const short8* Bp = (const short8*)Bt + (nt * 16 + li) * 128 + q;
    f32x4 acc = {0.f, 0.f, 0.f, 0.f};
#pragma unroll
    for (int kk = 0; kk < 128; kk += 4) acc = MFMA16(Ap[kk], Bp[kk], acc);
    int col = nt * 16 + li;
    float bias = (col < 2048) ? b_lstm[col] : vis2g_b[col - 2048];
#pragma unroll
    for (int r = 0; r < 4; r++) {
        int row = mt * 16 + q * 4 + r;
        C[row * NC + col] = acc[r] + bias;
    }
}

// preF in TRANSPOSED-fragment order: preF[((rowtile*160 + ct)*256 + lane*4) + r]
//   = pre[row = rowtile*16 + (lane&15)][col = ct*16 + (lane>>4)*4 + r]
// emb pre-converted to bf16 -> A-frags are direct short8 loads (no cvt, half BW).
__global__ __launch_bounds__(256) void pre_gemm(const int* __restrict__ seqz,
                                                const __hip_bfloat16* __restrict__ embB,
                                                const short8* __restrict__ Bsw,   // 160 tiles, frag order
                                                const float* __restrict__ visC,
                                                __hip_bfloat16* __restrict__ preF) {
    __shared__ short8 lds[2][1024];
    int w = threadIdx.x >> 6, lane = threadIdx.x & 63, li = lane & 15, q = lane >> 4;
    int r0 = blockIdx.x * 128 + w * 32;

    short8 a0[16], a1[16];
    {
        int row = r0 + li;
        int t = row >> 8, b = row & 255;
        int wid_ = (t == 0) ? (VOCAB + 1) : seqz[b * TT + (t - 1)];
        const short8* er = (const short8*)(embB + (size_t)wid_ * WORD) + q;
#pragma unroll
        for (int kt = 0; kt < 16; kt++) a0[kt] = er[kt * 4];
        row = r0 + 16 + li; t = row >> 8; b = row & 255;
        wid_ = (t == 0) ? (VOCAB + 1) : seqz[b * TT + (t - 1)];
        er = (const short8*)(embB + (size_t)wid_ * WORD) + q;
#pragma unroll
        for (int kt = 0; kt < 16; kt++) a1[kt] = er[kt * 4];
    }

    int t0 = blockIdx.y * 20, t1 = t0 + 20;   // 8 chunks x 20 = 160
    stage_tile(Bsw + (size_t)t0 * 1024, lds[0], w, lane);
    int ib = 0;
    for (int ct = t0; ct < t1; ++ct, ib ^= 1) {
        __syncthreads();
        if (ct + 1 < t1) stage_tile(Bsw + (size_t)(ct + 1) * 1024, lds[ib ^ 1], w, lane);
        const short8* B = lds[ib];
        f32x4 c0 = {0.f,0.f,0.f,0.f}, c1 = {0.f,0.f,0.f,0.f};
#pragma unroll
        for (int kt = 0; kt < 16; kt++) {
            short8 bv = B[kt * 64 + lane];
            // TRANSPOSED: A = W-frag, B = emb-frag -> lane holds batch row li, gate cols ct*16+q*4..+3
            c0 = MFMA16(bv, a0[kt], c0);
            c1 = MFMA16(bv, a1[kt], c1);
        }
        int col0 = ct * 16 + q * 4;
        size_t tb0 = ((size_t)(r0 >> 4) * 160 + ct) * 256 + lane * 4;
        size_t tb1 = tb0 + (size_t)160 * 256;
        float4 v0 = *(const float4*)(visC + ((r0 + li) & 255) * NC + col0);
        float4 v1 = *(const float4*)(visC + ((r0 + 16 + li) & 255) * NC + col0);
        preF[tb0 + 0] = __float2bfloat16(c0[0] + v0.x);
        preF[tb0 + 1] = __float2bfloat16(c0[1] + v0.y);
        preF[tb0 + 2] = __float2bfloat16(c0[2] + v0.z);
        preF[tb0 + 3] = __float2bfloat16(c0[3] + v0.w);
        preF[tb1 + 0] = __float2bfloat16(c1[0] + v1.x);
        preF[tb1 + 1] = __float2bfloat16(c1[1] + v1.y);
        preF[tb1 + 2] = __float2bfloat16(c1[2] + v1.z);
        preF[tb1 + 3] = __float2bfloat16(c1[3] + v1.w);
    }
}

// ---------------- persistent recurrence kernel (single chain, r4 structure) ----------------
// 512 blocks x 1 wave (cooperative). Wave (bt,jt): batch rows bt*16..+15, gate cols
// jt*16..+15 of the 5 gate blocks. bt = wid>>5 (measured-best mapping).
// This is the r4 measured-best structure (~305us) + the r8 race fix + fast transcendentals.
// Per step: poll 32 per-group flags (one 32-lane system load) -> FENCE -> gather 32x8B h
// -> issue next-step preF prefetch (sits behind gather in vmcnt queue; retires under
// MFMA+epilogue) -> MFMA -> epilogue -> h store + S store -> vmcnt(0) -> own flag = t+1.
// RACE FIX (r8): poll and gather are both RELAXED; without a compiler fence the gather
// can be hoisted above the poll (LICM). asm volatile("" ::: "memory") pins it.
// Poll bounded: logic bug -> fast wrong answer, never a hang.
__global__ __launch_bounds__(64, 1) void lstm_persist(const short8* __restrict__ WHsw,
                                                      const __hip_bfloat16* __restrict__ preF,
                                                      __hip_bfloat16* __restrict__ h0,
                                                      __hip_bfloat16* __restrict__ h1,
                                                      __hip_bfloat16* __restrict__ S,
                                                      int* __restrict__ flags) {
    __shared__ short8 ldsB[4096];   // 64 KB: 4 gate W-tiles x 16KB, fragment order
    int wid = blockIdx.x;           // 0..511
    int bt = wid >> 5, jt = wid & 31;
    int lane = threadIdx.x;
    int li = lane & 15, q = lane >> 4;

    // stage W tiles for gates 0..3 -> LDS (linear copy of frag-order tiles)
#pragma unroll
    for (int g = 0; g < 4; ++g) {
        const char* src = (const char*)(WHsw + (size_t)(g * 32 + jt) * 1024) + lane * 16;
        char* dst = (char*)ldsB + g * 16384;
#pragma unroll
        for (int i = 0; i < 16; ++i) gload_lds16(src + i * 1024, dst + i * 1024);
    }
    // sentinel-gate W tile -> registers
    short8 b4[16];
    const short8* B4 = WHsw + (size_t)(128 + jt) * 1024 + lane;
#pragma unroll
    for (int kt = 0; kt < 16; ++kt) b4[kt] = B4[kt * 64];
    __syncthreads();   // drains vmcnt -> gload_lds data usable

    int* flagp = flags + bt * 64;         // 32 flag words per group (2 cachelines)
    f32x4 cacc = {0.f, 0.f, 0.f, 0.f};    // c[row bt*16+li][cols jt*16+q*4..+3]

    int hin  = (bt * 16 + li) * 1024 + q * 16;                // h frag load base (bytes)
    int hout = (bt * 16 + li) * 1024 + (jt * 16 + q * 4) * 2; // h/S store base (bytes)

    // preF stream: ull index = t*163840 + bt*10240 + g*2048 + jt*64 + lane
    const ull* ppw = (const ull*)preF + ((size_t)bt * 160 + jt) * 64 + lane;

    ull ppA[5], ppB[5];
#pragma unroll
    for (int g = 0; g < 5; ++g) ppA[g] = ppw[g * 2048];

    ull hf[32];

#define LSTM_STEP(T, HC, HN, PPC, PPN)                                             \
  {                                                                                \
    if ((T) > 0) {                                                                 \
      int it = 0;                                                                  \
      while (true) {                                                               \
        int v = (T);                                                               \
        if (lane < 32)                                                             \
          v = __hip_atomic_load(flagp + lane, __ATOMIC_RELAXED,                    \
                                __HIP_MEMORY_SCOPE_SYSTEM);                        \
        if (__all(v >= (T))) break;                                                \
        if (++it > 30000) break;   /* bounded: fail loud, never hang */            \
        __builtin_amdgcn_s_sleep(1);                                               \
      }                                                                            \
    }                                                                              \
    asm volatile("" ::: "memory");   /* pin gather AFTER poll (r8 race fix) */     \
    const ull* hp = (const ull*)((const char*)(HC) + hin);                         \
    _Pragma("unroll") for (int kt = 0; kt < 16; ++kt) {                            \
      hf[2 * kt]     = __hip_atomic_load(hp + kt * 8, __ATOMIC_RELAXED,            \
                                         __HIP_MEMORY_SCOPE_SYSTEM);               \
      hf[2 * kt + 1] = __hip_atomic_load(hp + kt * 8 + 1, __ATOMIC_RELAXED,        \
                                         __HIP_MEMORY_SCOPE_SYSTEM);               \
    }                                                                              \
    if ((T) + 1 < TT) {                                                            \
      const ull* pn = ppw + (size_t)((T) + 1) * 163840;                            \
      _Pragma("unroll") for (int g = 0; g < 5; ++g) (PPN)[g] = pn[g * 2048];       \
    }                                                                              \
    f32x4 g0 = {0.f, 0.f, 0.f, 0.f}, g1 = g0, g2 = g0, g3 = g0, g4 = g0;           \
    _Pragma("unroll") for (int kt = 0; kt < 16; ++kt) {                            \
      U16 hv; hv.u[0] = hf[2 * kt]; hv.u[1] = hf[2 * kt + 1];                      \
      short8 bv = hv.s8;                                                           \
      g0 = MFMA16(ldsB[       kt * 64 + lane], bv, g0);                            \
      g1 = MFMA16(ldsB[1024 + kt * 64 + lane], bv, g1);                            \
      g2 = MFMA16(ldsB[2048 + kt * 64 + lane], bv, g2);                            \
      g3 = MFMA16(ldsB[3072 + kt * 64 + lane], bv, g3);                            \
      g4 = MFMA16(b4[kt], bv, g4);                                                 \
    }                                                                              \
    ull hvout = 0ull, svout = 0ull;                                                \
    _Pragma("unroll") for (int r = 0; r < 4; ++r) {                                \
      float ig = sigf(g0[r] + bf2f((short)((PPC)[0] >> (16 * r))));                \
      float fg = sigf(g1[r] + bf2f((short)((PPC)[1] >> (16 * r))));                \
      float gg = tanhf_fast(g2[r] + bf2f((short)((PPC)[2] >> (16 * r))));          \
      float og = sigf(g3[r] + bf2f((short)((PPC)[3] >> (16 * r))));                \
      float gp = sigf(g4[r] + bf2f((short)((PPC)[4] >> (16 * r))));                \
      float cn = fg * cacc[r] + ig * gg;                                           \
      float tc = tanhf_fast(cn);                                                   \
      cacc[r] = cn;                                                                \
      hvout |= ((ull)(unsigned short)f2bfs(og * tc)) << (16 * r);                  \
      svout |= ((ull)(unsigned short)f2bfs(gp * tc)) << (16 * r);                  \
    }                                                                              \
    __hip_atomic_store((ull*)((char*)(HN) + hout), hvout,                          \
                       __ATOMIC_RELAXED, __HIP_MEMORY_SCOPE_SYSTEM);               \
    *(ull*)((char*)S + (size_t)(T) * 262144 + hout) = svout;                       \
    asm volatile("s_waitcnt vmcnt(0)" ::: "memory");                               \
    if (lane == 0)                                                                 \
      __hip_atomic_store(flagp + jt, (T) + 1, __ATOMIC_RELAXED,                    \
                         __HIP_MEMORY_SCOPE_SYSTEM);                               \
  }

    for (int t = 0; t < TT; t += 2) {
        LSTM_STEP(t,     h0, h1, ppA, ppB);
        LSTM_STEP(t + 1, h1, h0, ppB, ppA);
    }
#undef LSTM_STEP
}

// ---------------- fused output GEMM + sum-exp ----------------

__global__ __launch_bounds__(256) void lse_gemm(const short8* __restrict__ S8,
                                                const short8* __restrict__ Bsw,
                                                const float* __restrict__ ob,
                                                float* __restrict__ sumexp) {
    __shared__ short8 lds[2][1024];
    int w = threadIdx.x >> 6, lane = threadIdx.x & 63, li = lane & 15, q = lane >> 4;
    int r0 = blockIdx.x * 128 + w * 32;
    short8 a0[16], a1[16];
    const short8* Sp0 = S8 + (size_t)(r0 + li) * 64 + q;
    const short8* Sp1 = S8 + (size_t)(r0 + 16 + li) * 64 + q;
#pragma unroll
    for (int kt = 0; kt < 16; kt++) { a0[kt] = Sp0[kt * 4]; a1[kt] = Sp1[kt * 4]; }

    float s0[4] = {0.f,0.f,0.f,0.f}, s1[4] = {0.f,0.f,0.f,0.f};
    int t0 = blockIdx.y * 40;
    int t1 = t0 + 40 < NTILES ? t0 + 40 : NTILES;   // last chunk = 26

    stage_tile(Bsw + (size_t)t0 * 1024, lds[0], w, lane);
    int ib = 0;
    for (int ct = t0; ct < t1; ++ct, ib ^= 1) {
        __syncthreads();
        if (ct + 1 < t1) stage_tile(Bsw + (size_t)(ct + 1) * 1024, lds[ib ^ 1], w, lane);
        const short8* B = lds[ib];
        f32x4 c0 = {0.f,0.f,0.f,0.f}, c1 = {0.f,0.f,0.f,0.f};
#pragma unroll
        for (int kt = 0; kt < 16; kt++) {
            short8 bv = B[kt * 64 + lane];
            c0 = MFMA16(a0[kt], bv, c0);
            c1 = MFMA16(a1[kt], bv, c1);
        }
        int col = ct * 16 + li;
        if (col < NV) {
            float obv = ob[col];
#pragma unroll
            for (int r = 0; r < 4; r++) {
                s0[r] += __expf(c0[r] + obv);
                s1[r] += __expf(c1[r] + obv);
            }
        }
    }
#pragma unroll
    for (int off = 1; off < 16; off <<= 1) {
#pragma unroll
        for (int r = 0; r < 4; r++) { s0[r] += __shfl_xor(s0[r], off); s1[r] += __shfl_xor(s1[r], off); }
    }
    if (li == 0) {
#pragma unroll
        for (int r = 0; r < 4; r++) {
            atomicAdd(&sumexp[r0 + q * 4 + r], s0[r]);
            atomicAdd(&sumexp[r0 + 16 + q * 4 + r], s1[r]);
        }
    }
}

// out[row] = mask * (dot(S[row], out_W[:,tgt]) + ob[tgt] - log(sumexp[row]))
__global__ __launch_bounds__(256) void finalize_k(const __hip_bfloat16* __restrict__ S,
                                                  const __hip_bfloat16* __restrict__ Wt,
                                                  const float* __restrict__ ob,
                                                  const int* __restrict__ seqz,
                                                  const float* __restrict__ sumexp,
                                                  float* __restrict__ out) {
    int w = threadIdx.x >> 6, lane = threadIdx.x & 63;
    int row = blockIdx.x * 4 + w;        // 16384 rows, row = t*256 + b
    int t = row >> 8, b = row & 255;
    int tgt = seqz[b * TT + t];
    short8 sv = ((const short8*)(S + (size_t)row * 512))[lane];
    short8 wv = ((const short8*)(Wt + (size_t)tgt * 512))[lane];
    float d = 0.f;
#pragma unroll
    for (int i = 0; i < 8; i++) d += bf2f(sv[i]) * bf2f(wv[i]);
#pragma unroll
    for (int off = 1; off < 64; off <<= 1) d += __shfl_xor(d, off);
    if (lane == 0) {
        bool mk = (t == 0) || (seqz[b * TT + t - 1] != 0);
        out[row] = mk ? (d + ob[tgt] - logf(sumexp[row])) : 0.f;
    }
}

// ---------------- host ----------------

extern "C" void kernel_launch(void* const* d_in, const int* in_sizes, int n_in,
                              void* d_out, int out_size, void* d_ws, size_t ws_size,
                              hipStream_t stream) {
    const float* vis     = (const float*)d_in[0];
    const int*   seqz    = (const int*)d_in[1];
    const float* emb     = (const float*)d_in[2];
    const float* W_ih    = (const float*)d_in[3];
    const float* W_hh    = (const float*)d_in[4];
    const float* b_lstm  = (const float*)d_in[5];
    const float* vis2g_W = (const float*)d_in[6];
    const float* vis2g_b = (const float*)d_in[7];
    const float* w2g_W   = (const float*)d_in[8];
    const float* h2g_W   = (const float*)d_in[9];
    const float* out_W   = (const float*)d_in[10];
    const float* out_b   = (const float*)d_in[11];
    float* out = (float*)d_out;

    char* p = (char*)d_ws;
    auto carve = [&](size_t bytes) {
        void* r = (void*)p;
        p += (bytes + 255) & ~(size_t)255;
        return r;
    };
    __hip_bfloat16* WcatW = (__hip_bfloat16*)carve((size_t)NC * 512 * 2);       // [2560][512]
    __hip_bfloat16* WcatH = (__hip_bfloat16*)carve((size_t)NC * 512 * 2);       // [2560][512]
    __hip_bfloat16* visWt = (__hip_bfloat16*)carve((size_t)NC * 1024 * 2);      // [2560][1024]
    __hip_bfloat16* outWt = (__hip_bfloat16*)carve((size_t)NVP * 512 * 2);      // [10016][512]
    short8*         outSw = (short8*)carve((size_t)NTILES * 16384);             // frag order
    short8*         preBsw= (short8*)carve((size_t)160 * 16384);                // frag order
    short8*         WHsw  = (short8*)carve((size_t)160 * 16384);                // frag order
    __hip_bfloat16* visB  = (__hip_bfloat16*)carve((size_t)256 * 1024 * 2);
    __hip_bfloat16* embB  = (__hip_bfloat16*)carve((size_t)(VOCAB + 2) * WORD * 2); // emb bf16
    float*          visC  = (float*)carve((size_t)256 * NC * 4);
    __hip_bfloat16* preF  = (__hip_bfloat16*)carve((size_t)TT * 256 * NC * 2);  // 84 MB, frag order
    __hip_bfloat16* hb0   = (__hip_bfloat16*)carve((size_t)256 * 512 * 2);
    __hip_bfloat16* hb1   = (__hip_bfloat16*)carve((size_t)256 * 512 * 2);
    __hip_bfloat16* S     = (__hip_bfloat16*)carve((size_t)TT * 256 * 512 * 2);
    float*          sume  = (float*)carve((size_t)TT * 256 * 4);
    int*            bars  = (int*)carve((size_t)16 * 64 * 4);                   // 16 groups x 32 flag words

    dim3 tb(32, 8);
    // WcatW: word -> [gates | w2g];  WcatH: h -> [gates | h2g]   (both [2560][512] = [N][K])
    transpose_cvt<<<dim3(64, 16), tb, 0, stream>>>(W_ih + 1024 * 2048, 512, 2048, 2048, WcatW, 512, 2048);
    transpose_cvt<<<dim3(16, 16), tb, 0, stream>>>(w2g_W, 512, 512, 512, WcatW + 2048 * 512, 512, 512);
    transpose_cvt<<<dim3(64, 16), tb, 0, stream>>>(W_hh, 512, 2048, 2048, WcatH, 512, 2048);
    transpose_cvt<<<dim3(16, 16), tb, 0, stream>>>(h2g_W, 512, 512, 512, WcatH + 2048 * 512, 512, 512);
    // visWt: vis -> [gates | vis2g]  [2560][1024]
    transpose_cvt<<<dim3(64, 32), tb, 0, stream>>>(W_ih, 1024, 2048, 2048, visWt, 1024, 2048);
    transpose_cvt<<<dim3(16, 32), tb, 0, stream>>>(vis2g_W, 1024, 512, 512, visWt + 2048 * 1024, 1024, 512);
    // out_W transposed, zero-padded to 10016 rows
    transpose_cvt<<<dim3(313, 16), tb, 0, stream>>>(out_W, 512, NV, NV, outWt, 512, NVP);
    // fragment-order swizzles
    swizzle_frag<<<2504, 256, 0, stream>>>((const short8*)outWt, outSw, NTILES);
    swizzle_frag<<<640, 256, 0, stream>>>((const short8*)WcatW, preBsw, 160);
    swizzle_frag<<<640, 256, 0, stream>>>((const short8*)WcatH, WHsw, 160);

    // h0 = zeros (step-0 input); flags = 0; sumexp = 0
    hipMemsetAsync(hb0, 0, (size_t)256 * 512 * 2, stream);
    hipMemsetAsync(bars, 0, (size_t)16 * 64 * 4, stream);
    hipMemsetAsync(sume, 0, (size_t)TT * 256 * 4, stream);

    cvt_vis<<<1024, 256, 0, stream>>>(vis, visB);
    cvt_emb<<<2501, 256, 0, stream>>>(emb, (short8*)embB, (VOCAB + 2) * WORD / 8);
    gemm_vis<<<640, 256, 0, stream>>>(visB, visWt, b_lstm, vis2g_b, visC);
    pre_gemm<<<dim3(128, 8), 256, 0, stream>>>(seqz, embB, preBsw, visC, preF);

    // all 64 recurrence steps in one cooperative persistent kernel (single chain)
    {
        const short8* WHsw_c = (const short8*)WHsw;
        const __hip_bfloat16* preF_c = (const __hip_bfloat16*)preF;
        __hip_bfloat16* h0a = hb0;
        __hip_bfloat16* h1a = hb1;
        __hip_bfloat16* Sa = S;
        int* barsa = bars;
        void* kargs[6] = { &WHsw_c, &preF_c, &h0a, &h1a, &Sa, &barsa };
        hipLaunchCooperativeKernel((void*)lstm_persist, dim3(512), dim3(64), kargs, 0, stream);
    }

    lse_gemm<<<dim3(128, 16), 256, 0, stream>>>((const short8*)S, outSw, out_b, sume);
    finalize_k<<<4096, 256, 0, stream>>>(S, outWt, out_b, seqz, sume, out);
}